// Round 5
// baseline (1605.498 us; speedup 1.0000x reference)
//
#include <hip/hip_runtime.h>
#include <stdint.h>

#define N_TOK   65536
#define MDIM    2048
#define FDIM    512
#define SCALE_F 10.0f
#define TAU_F   2e-5f
#define QCAP    16384

typedef __attribute__((ext_vector_type(8))) unsigned short u16x8;
typedef __attribute__((ext_vector_type(8))) __bf16 bf16x8;
typedef __attribute__((ext_vector_type(4))) float f32x4;

__device__ __forceinline__ unsigned short f2bf(float f) {
  unsigned int u = __builtin_bit_cast(unsigned int, f);
  u += 0x7fffu + ((u >> 16) & 1u);   // round-to-nearest-even
  return (unsigned short)(u >> 16);
}
__device__ __forceinline__ float bf2f(unsigned short b) {
  return __builtin_bit_cast(float, (unsigned int)b << 16);
}
__device__ __forceinline__ f32x4 mfma16(u16x8 a, u16x8 b, f32x4 c) {
  return __builtin_amdgcn_mfma_f32_16x16x32_bf16(
      __builtin_bit_cast(bf16x8, a), __builtin_bit_cast(bf16x8, b), c, 0, 0, 0);
}
// async global->LDS, 16B per lane; lds ptr must be wave-uniform base
__device__ __forceinline__ void gload16(const unsigned short* g, unsigned short* l) {
  __builtin_amdgcn_global_load_lds(
      (const __attribute__((address_space(1))) unsigned int*)g,   // NOLINT
      (__attribute__((address_space(3))) unsigned int*)l,          // NOLINT
      16, 0, 0);
}
// column-slot swizzle (16B slots) within a 128x32-short LDS tile
__device__ __forceinline__ int swz(int row) {
  return (row & 3) ^ ((row >> 2) & 3);
}

// ---------------- zero updates + queue counter ----------------
__global__ __launch_bounds__(256) void zero_k(float* __restrict__ updates,
                                              int* __restrict__ qcount) {
  const size_t i = ((size_t)blockIdx.x * 256 + threadIdx.x) * 4;
  *(float4*)(updates + i) = make_float4(0.f, 0.f, 0.f, 0.f);
  if (blockIdx.x == 0 && threadIdx.x == 0) *qcount = 0;
}

// ---------------- memory_norm -> bf16 hi/lo ----------------
__global__ __launch_bounds__(64) void prep_memory_k(
    const float* __restrict__ mem, unsigned short* __restrict__ Bh,
    unsigned short* __restrict__ Bl) {
  const int m = blockIdx.x;
  const int lane = threadIdx.x;
  const float* row = mem + (size_t)m * FDIM;
  float4 a = *(const float4*)(row + lane * 4);
  float4 b = *(const float4*)(row + 256 + lane * 4);
  float s = a.x * a.x + a.y * a.y + a.z * a.z + a.w * a.w +
            b.x * b.x + b.y * b.y + b.z * b.z + b.w * b.w;
  #pragma unroll
  for (int off = 1; off < 64; off <<= 1) s += __shfl_xor(s, off);
  const float rn = 1.0f / sqrtf(fmaxf(s, 1e-12f));
  float v[8] = {a.x, a.y, a.z, a.w, b.x, b.y, b.z, b.w};
  #pragma unroll
  for (int h = 0; h < 2; ++h) {
    ushort4 hs, lo;
    #pragma unroll
    for (int q = 0; q < 4; ++q) {
      float x = v[h * 4 + q] * rn;
      unsigned short hb = f2bf(x);
      ((unsigned short*)&hs)[q] = hb;
      ((unsigned short*)&lo)[q] = f2bf(x - bf2f(hb));
    }
    const size_t e = (size_t)m * FDIM + h * 256 + lane * 4;
    *(ushort4*)(Bh + e) = hs;
    *(ushort4*)(Bl + e) = lo;
  }
}

// ---------------- transpose Bh [M][F] -> Bt [F][M] ----------------
__global__ __launch_bounds__(256) void transpose_k(
    const unsigned short* __restrict__ Bh, unsigned short* __restrict__ Bt) {
  __shared__ unsigned short t[32][33];
  const int m0 = blockIdx.x * 32, f0 = blockIdx.y * 32;
  const int tx = threadIdx.x & 31, ty = threadIdx.x >> 5;
  #pragma unroll
  for (int r = ty; r < 32; r += 8)
    t[r][tx] = Bh[(size_t)(m0 + r) * FDIM + f0 + tx];
  __syncthreads();
  #pragma unroll
  for (int r = ty; r < 32; r += 8)
    Bt[(size_t)(f0 + r) * MDIM + m0 + tx] = t[tx][r];
}

// ---------------- input row inv-norms (f32) ----------------
__global__ __launch_bounds__(256) void input_norms_k(
    const float* __restrict__ inp, float* __restrict__ inv_n) {
  const int row = blockIdx.x * 4 + (threadIdx.x >> 6);
  const int lane = threadIdx.x & 63;
  const float* x = inp + (size_t)row * FDIM;
  float4 a = *(const float4*)(x + lane * 4);
  float4 b = *(const float4*)(x + 256 + lane * 4);
  float s = a.x * a.x + a.y * a.y + a.z * a.z + a.w * a.w +
            b.x * b.x + b.y * b.y + b.z * b.z + b.w * b.w;
  #pragma unroll
  for (int off = 1; off < 64; off <<= 1) s += __shfl_xor(s, off);
  if (lane == 0) inv_n[row] = 1.0f / sqrtf(fmaxf(s, 1e-12f));
}

// ---------------- inputs_norm chunk -> bf16 hi/lo ----------------
__global__ __launch_bounds__(256) void prep_a_k(
    const float* __restrict__ inp, const float* __restrict__ inv_n,
    unsigned short* __restrict__ Ah, unsigned short* __restrict__ Al,
    int baseRow) {
  const size_t q4 = (size_t)blockIdx.x * 256 + threadIdx.x;
  const size_t e = q4 * 4;
  const int lrow = (int)(e >> 9);
  const float rn = inv_n[baseRow + lrow];
  float4 x = *(const float4*)(inp + (size_t)(baseRow + lrow) * FDIM + (e & 511));
  float xv[4] = {x.x, x.y, x.z, x.w};
  ushort4 hs, lo;
  #pragma unroll
  for (int q = 0; q < 4; ++q) {
    float v = xv[q] * rn;
    unsigned short hb = f2bf(v);
    ((unsigned short*)&hs)[q] = hb;
    ((unsigned short*)&lo)[q] = f2bf(v - bf2f(hb));
  }
  *(ushort4*)(Ah + e) = hs;
  *(ushort4*)(Al + e) = lo;
}

// ---------------- GEMM: C[M][N] = A[M][K] * B[N][K]^T, fp32 C ----------------
// global_load_lds(16B) staging into linear [128][32]-short tiles; global source
// columns pre-swizzled, LDS reads apply the same swizzle (both-sides rule).
template <bool SPLIT>
__global__ __launch_bounds__(256) void gemm_bt_k(
    const unsigned short* __restrict__ Ah, const unsigned short* __restrict__ Al,
    const unsigned short* __restrict__ Bh, const unsigned short* __restrict__ Bl,
    float* __restrict__ C, int M, int N, int K) {
  __shared__ alignas(16) unsigned short sAh[128 * 32];
  __shared__ alignas(16) unsigned short sBh[128 * 32];
  __shared__ alignas(16) unsigned short sAl[SPLIT ? 128 * 32 : 8];
  __shared__ alignas(16) unsigned short sBl[SPLIT ? 128 * 32 : 8];

  const int tid = threadIdx.x;
  const int lane = tid & 63, wave = tid >> 6;
  const int wr = wave >> 1, wc = wave & 1;
  const int lr = lane & 15, ls = lane >> 4;
  const int m0 = blockIdx.y * 128, n0 = blockIdx.x * 128;

  f32x4 acc[4][4] = {};

  // staging: per wave two issues (h=0,1): rows u*16..u*16+15, u=wave*2+h.
  // lane -> row = u*16 + (lane>>2), 16B-slot = lane&3; source col-slot swizzled.
  const int row0 = (wave * 2 + 0) * 16 + (lane >> 2);
  const int row1 = (wave * 2 + 1) * 16 + (lane >> 2);
  const int gs0 = ((lane & 3) ^ swz(row0)) * 8;
  const int gs1 = ((lane & 3) ^ swz(row1)) * 8;

  const unsigned short* gA0 = Ah + (size_t)(m0 + row0) * K + gs0;
  const unsigned short* gA1 = Ah + (size_t)(m0 + row1) * K + gs1;
  const unsigned short* gB0 = Bh + (size_t)(n0 + row0) * K + gs0;
  const unsigned short* gB1 = Bh + (size_t)(n0 + row1) * K + gs1;
  const unsigned short* gAl0 = nullptr; const unsigned short* gAl1 = nullptr;
  const unsigned short* gBl0 = nullptr; const unsigned short* gBl1 = nullptr;
  if constexpr (SPLIT) {
    gAl0 = Al + (size_t)(m0 + row0) * K + gs0;
    gAl1 = Al + (size_t)(m0 + row1) * K + gs1;
    gBl0 = Bl + (size_t)(n0 + row0) * K + gs0;
    gBl1 = Bl + (size_t)(n0 + row1) * K + gs1;
  }
  // wave-uniform LDS bases (hardware adds lane*16B)
  unsigned short* lA0 = &sAh[(wave * 2 + 0) * 512];
  unsigned short* lA1 = &sAh[(wave * 2 + 1) * 512];
  unsigned short* lB0 = &sBh[(wave * 2 + 0) * 512];
  unsigned short* lB1 = &sBh[(wave * 2 + 1) * 512];
  unsigned short* lAl0 = SPLIT ? &sAl[(wave * 2 + 0) * 512] : nullptr;
  unsigned short* lAl1 = SPLIT ? &sAl[(wave * 2 + 1) * 512] : nullptr;
  unsigned short* lBl0 = SPLIT ? &sBl[(wave * 2 + 0) * 512] : nullptr;
  unsigned short* lBl1 = SPLIT ? &sBl[(wave * 2 + 1) * 512] : nullptr;

  const int nk = K >> 5;
  for (int ks = 0; ks < nk; ++ks) {
    gload16(gA0, lA0); gload16(gA1, lA1);
    gload16(gB0, lB0); gload16(gB1, lB1);
    if constexpr (SPLIT) {
      gload16(gAl0, lAl0); gload16(gAl1, lAl1);
      gload16(gBl0, lBl0); gload16(gBl1, lBl1);
    }
    gA0 += 32; gA1 += 32; gB0 += 32; gB1 += 32;
    if constexpr (SPLIT) { gAl0 += 32; gAl1 += 32; gBl0 += 32; gBl1 += 32; }
    __syncthreads();  // compiler drains vmcnt before barrier -> data visible

    u16x8 fa[4], fb[4], fal[4], fbl[4];
    #pragma unroll
    for (int i = 0; i < 4; ++i) {
      const int ra = wr * 64 + i * 16 + lr;
      const int rb = wc * 64 + i * 16 + lr;
      const int ca = (ls ^ swz(ra)) * 8;
      const int cb = (ls ^ swz(rb)) * 8;
      fa[i] = *(const u16x8*)&sAh[ra * 32 + ca];
      fb[i] = *(const u16x8*)&sBh[rb * 32 + cb];
      if constexpr (SPLIT) {
        fal[i] = *(const u16x8*)&sAl[ra * 32 + ca];
        fbl[i] = *(const u16x8*)&sBl[rb * 32 + cb];
      }
    }
    #pragma unroll
    for (int i = 0; i < 4; ++i)
      #pragma unroll
      for (int j = 0; j < 4; ++j) {
        acc[i][j] = mfma16(fa[i], fb[j], acc[i][j]);
        if constexpr (SPLIT) {
          acc[i][j] = mfma16(fal[i], fb[j], acc[i][j]);
          acc[i][j] = mfma16(fa[i], fbl[j], acc[i][j]);
        }
      }
    __syncthreads();  // protect LDS before next iteration's overwrite
  }

  #pragma unroll
  for (int i = 0; i < 4; ++i) {
    const int rrow = m0 + wr * 64 + i * 16 + ls * 4;
    #pragma unroll
    for (int j = 0; j < 4; ++j) {
      const int col = n0 + wc * 64 + j * 16 + lr;
      #pragma unroll
      for (int q = 0; q < 4; ++q)
        C[(size_t)(rrow + q) * N + col] = acc[i][j][q];
    }
  }
}

// -------- row softmax + top-2 + P(bf16) + scatter / queue ambiguous --------
__global__ __launch_bounds__(256) void softmax_scatter_k(
    const float* __restrict__ S, unsigned short* __restrict__ P,
    const float* __restrict__ inp, const float* __restrict__ inv_n,
    float* __restrict__ updates, int* __restrict__ queue,
    int* __restrict__ qcount, int baseRow) {
  const int widx = blockIdx.x * 4 + (threadIdx.x >> 6);
  const int lane = threadIdx.x & 63;
  const float* srow = S + (size_t)widx * MDIM;
  float4 v[8];
  float m1 = -3.4e38f, m2 = -3.4e38f;
  int i1 = 0x7fffffff, i2 = 0x7fffffff;
  #pragma unroll
  for (int i = 0; i < 8; ++i) {
    v[i] = *(const float4*)(srow + i * 256 + lane * 4);
    const float xs[4] = {v[i].x, v[i].y, v[i].z, v[i].w};
    #pragma unroll
    for (int q = 0; q < 4; ++q) {
      const float x = xs[q];
      const int idx = i * 256 + lane * 4 + q;
      if (x > m1 || (x == m1 && idx < i1)) { m2 = m1; i2 = i1; m1 = x; i1 = idx; }
      else if (x > m2 || (x == m2 && idx < i2)) { m2 = x; i2 = idx; }
    }
  }
  #pragma unroll
  for (int off = 1; off < 64; off <<= 1) {  // butterfly top-2 merge (disjoint groups)
    const float n1 = __shfl_xor(m1, off), n2 = __shfl_xor(m2, off);
    const int j1 = __shfl_xor(i1, off), j2 = __shfl_xor(i2, off);
    if (n1 > m1 || (n1 == m1 && j1 < i1)) {
      if (m1 > n2 || (m1 == n2 && i1 < j2)) { m2 = m1; i2 = i1; }
      else { m2 = n2; i2 = j2; }
      m1 = n1; i1 = j1;
    } else if (n1 > m2 || (n1 == m2 && j1 < i2)) { m2 = n1; i2 = j1; }
  }
  float sum = 0.0f;
  #pragma unroll
  for (int i = 0; i < 8; ++i) {
    v[i].x = __expf(SCALE_F * (v[i].x - m1)); sum += v[i].x;
    v[i].y = __expf(SCALE_F * (v[i].y - m1)); sum += v[i].y;
    v[i].z = __expf(SCALE_F * (v[i].z - m1)); sum += v[i].z;
    v[i].w = __expf(SCALE_F * (v[i].w - m1)); sum += v[i].w;
  }
  #pragma unroll
  for (int off = 1; off < 64; off <<= 1) sum += __shfl_xor(sum, off);
  const float rs = 1.0f / sum;
  #pragma unroll
  for (int i = 0; i < 8; ++i) {
    ushort4 pk;
    pk.x = f2bf(v[i].x * rs); pk.y = f2bf(v[i].y * rs);
    pk.z = f2bf(v[i].z * rs); pk.w = f2bf(v[i].w * rs);
    *(ushort4*)(P + (size_t)widx * MDIM + i * 256 + lane * 4) = pk;
  }
  const int tok = baseRow + widx;
  bool do_scatter = true;
  if (m1 - m2 < TAU_F) {  // ambiguous at split-S noise scale -> fp64 refine
    int slot = 0;
    if (lane == 0) slot = atomicAdd(qcount, 1);
    slot = __shfl(slot, 0);
    if (slot < QCAP) {
      if (lane == 0) {
        queue[slot * 3] = tok; queue[slot * 3 + 1] = i1; queue[slot * 3 + 2] = i2;
      }
      do_scatter = false;
    }
  }
  if (do_scatter) {
    const float rn = inv_n[tok];
    const float* xrow = inp + (size_t)tok * FDIM;
    float* urow = updates + (size_t)i1 * FDIM;
    #pragma unroll
    for (int h = 0; h < 2; ++h) {
      float4 xv = *(const float4*)(xrow + h * 256 + lane * 4);
      const int e = h * 256 + lane * 4;
      atomicAdd(&urow[e + 0], xv.x * rn);
      atomicAdd(&urow[e + 1], xv.y * rn);
      atomicAdd(&urow[e + 2], xv.z * rn);
      atomicAdd(&urow[e + 3], xv.w * rn);
    }
  }
}

// ------- fp64 two-candidate argmax refine + scatter (one wave/token) -------
// Split-S is accurate to ~3e-7, so the true argmax is within the S-top-2 for
// queued (gap < TAU) tokens; fp64 decides, smaller index on exact tie.
__global__ __launch_bounds__(256) void refine_k(
    const int* __restrict__ queue, const int* __restrict__ qcount,
    const float* __restrict__ inp, const float* __restrict__ mem,
    const float* __restrict__ inv_n, float* __restrict__ updates) {
  const int w = blockIdx.x * 4 + (threadIdx.x >> 6);
  const int lane = threadIdx.x & 63;
  int cnt = *qcount; if (cnt > QCAP) cnt = QCAP;
  if (w >= cnt) return;
  const int tok = queue[w * 3], a = queue[w * 3 + 1], b = queue[w * 3 + 2];
  const float* x = inp + (size_t)tok * FDIM;
  const float* ma = mem + (size_t)a * FDIM;
  const float* mb = mem + (size_t)b * FDIM;
  double da = 0, db = 0, na = 0, nb = 0;
  #pragma unroll
  for (int j = 0; j < 8; ++j) {
    const int e = lane * 8 + j;
    const double xv = x[e], av = ma[e], bv = mb[e];
    da += xv * av; na += av * av;
    db += xv * bv; nb += bv * bv;
  }
  #pragma unroll
  for (int off = 1; off < 64; off <<= 1) {
    da += __shfl_xor(da, off); na += __shfl_xor(na, off);
    db += __shfl_xor(db, off); nb += __shfl_xor(nb, off);
  }
  const double d1 = da / sqrt(fmax(na, 1e-12));
  const double d2 = db / sqrt(fmax(nb, 1e-12));
  int pick;
  if (d2 > d1) pick = b;
  else if (d2 < d1) pick = a;
  else pick = (a < b) ? a : b;        // exact fp64 tie: np.argmax first index
  const float rn = inv_n[tok];
  float* urow = updates + (size_t)pick * FDIM;
  #pragma unroll
  for (int h = 0; h < 2; ++h) {
    float4 xv = *(const float4*)(x + h * 256 + lane * 4);
    const int e = h * 256 + lane * 4;
    atomicAdd(&urow[e + 0], xv.x * rn);
    atomicAdd(&urow[e + 1], xv.y * rn);
    atomicAdd(&urow[e + 2], xv.z * rn);
    atomicAdd(&urow[e + 3], xv.w * rn);
  }
}

// ---------------- final blend (fp32 out) ----------------
__global__ __launch_bounds__(256) void final_update_k(
    const float* __restrict__ mem, const float* __restrict__ upd,
    float* __restrict__ out) {
  const size_t i = ((size_t)blockIdx.x * 256 + threadIdx.x) * 4;
  float4 m = *(const float4*)(mem + i);
  float4 u = *(const float4*)(upd + i);
  float4 r;
  r.x = m.x * 0.9f + u.x * 0.1f;
  r.y = m.y * 0.9f + u.y * 0.1f;
  r.z = m.z * 0.9f + u.z * 0.1f;
  r.w = m.w * 0.9f + u.w * 0.1f;
  *(float4*)(out + i) = r;
}

extern "C" void kernel_launch(void* const* d_in, const int* in_sizes, int n_in,
                              void* d_out, int out_size, void* d_ws, size_t ws_size,
                              hipStream_t stream) {
  const float* inputs = (const float*)d_in[0];
  const float* memory = (const float*)d_in[1];
  if (n_in >= 2 && in_sizes[0] != N_TOK * FDIM) {  // order guard
    inputs = (const float*)d_in[1];
    memory = (const float*)d_in[0];
  }
  float* out_mu = (float*)d_out;                       // [N][F] fp32
  float* out_um = out_mu + (size_t)N_TOK * FDIM;       // [M][F] fp32

  char* base = (char*)d_ws;
  size_t off = 0;
  auto take = [&](size_t bytes) -> char* {
    char* p = base + off;
    off = (off + bytes + 255) & ~(size_t)255;
    return p;
  };
  unsigned short* Bh = (unsigned short*)take((size_t)MDIM * FDIM * 2);
  unsigned short* Bl = (unsigned short*)take((size_t)MDIM * FDIM * 2);
  unsigned short* Bt = (unsigned short*)take((size_t)MDIM * FDIM * 2);
  float* inv_n = (float*)take((size_t)N_TOK * 4);
  float* updates = (float*)take((size_t)MDIM * FDIM * 4);
  int* queue = (int*)take((size_t)QCAP * 3 * 4);
  int* qcount = (int*)take(256);
  const size_t fixed = off;

  int chunkT = 8192;  // per-pass token chunk; shrink to fit ws
  while (chunkT > 128 && fixed + (size_t)chunkT * 14336 + 4096 > ws_size)
    chunkT >>= 1;
  if (fixed + (size_t)chunkT * 14336 + 4096 > ws_size) return;  // ws too small

  unsigned short* Ah = (unsigned short*)take((size_t)chunkT * FDIM * 2);
  unsigned short* Al = (unsigned short*)take((size_t)chunkT * FDIM * 2);
  float* Sbuf = (float*)take((size_t)chunkT * MDIM * 4);
  unsigned short* Pbuf = (unsigned short*)take((size_t)chunkT * MDIM * 2);

  zero_k<<<(MDIM * FDIM / 4) / 256, 256, 0, stream>>>(updates, qcount);
  prep_memory_k<<<MDIM, 64, 0, stream>>>(memory, Bh, Bl);
  transpose_k<<<dim3(MDIM / 32, FDIM / 32), 256, 0, stream>>>(Bh, Bt);
  input_norms_k<<<N_TOK / 4, 256, 0, stream>>>(inputs, inv_n);

  for (int baseRow = 0; baseRow < N_TOK; baseRow += chunkT) {
    prep_a_k<<<chunkT / 2, 256, 0, stream>>>(inputs, inv_n, Ah, Al, baseRow);
    gemm_bt_k<true><<<dim3(MDIM / 128, chunkT / 128), 256, 0, stream>>>(
        Ah, Al, Bh, Bl, Sbuf, chunkT, MDIM, FDIM);
    softmax_scatter_k<<<chunkT / 4, 256, 0, stream>>>(
        Sbuf, Pbuf, inputs, inv_n, updates, queue, qcount, baseRow);
    gemm_bt_k<false><<<dim3(FDIM / 128, chunkT / 128), 256, 0, stream>>>(
        Pbuf, nullptr, Bt, nullptr, out_mu + (size_t)baseRow * FDIM,
        chunkT, FDIM, MDIM);
  }
  refine_k<<<QCAP / 4, 256, 0, stream>>>(queue, qcount, inputs, memory,
                                         inv_n, updates);
  final_update_k<<<(MDIM * FDIM / 4) / 256, 256, 0, stream>>>(memory, updates, out_um);
}

// Round 6
// 1233.380 us; speedup vs baseline: 1.3017x; 1.3017x over previous
//
#include <hip/hip_runtime.h>
#include <stdint.h>

#define N_TOK   65536
#define MDIM    2048
#define FDIM    512
#define SCALE_F 10.0f
#define TAU_BF  1.2e-3f   // level-1: bf16-S ambiguity (12 sigma)
#define TAU_SP  2e-5f     // level-2: split-S ambiguity (~100 sigma)
#define QCAP    8192

typedef __attribute__((ext_vector_type(8))) unsigned short u16x8;
typedef __attribute__((ext_vector_type(8))) __bf16 bf16x8;
typedef __attribute__((ext_vector_type(4))) float f32x4;

__device__ __forceinline__ unsigned short f2bf(float f) {
  unsigned int u = __builtin_bit_cast(unsigned int, f);
  u += 0x7fffu + ((u >> 16) & 1u);   // round-to-nearest-even
  return (unsigned short)(u >> 16);
}
__device__ __forceinline__ float bf2f(unsigned short b) {
  return __builtin_bit_cast(float, (unsigned int)b << 16);
}
__device__ __forceinline__ f32x4 mfma16(u16x8 a, u16x8 b, f32x4 c) {
  return __builtin_amdgcn_mfma_f32_16x16x32_bf16(
      __builtin_bit_cast(bf16x8, a), __builtin_bit_cast(bf16x8, b), c, 0, 0, 0);
}

// ---------------- zero updates + queue counter ----------------
__global__ __launch_bounds__(256) void zero_k(float* __restrict__ updates,
                                              int* __restrict__ qcount) {
  const size_t i = ((size_t)blockIdx.x * 256 + threadIdx.x) * 4;
  *(float4*)(updates + i) = make_float4(0.f, 0.f, 0.f, 0.f);
  if (blockIdx.x == 0 && threadIdx.x == 0) *qcount = 0;
}

// ---------------- memory_norm -> bf16 hi/lo ----------------
__global__ __launch_bounds__(64) void prep_memory_k(
    const float* __restrict__ mem, unsigned short* __restrict__ Bh,
    unsigned short* __restrict__ Bl) {
  const int m = blockIdx.x;
  const int lane = threadIdx.x;
  const float* row = mem + (size_t)m * FDIM;
  float4 a = *(const float4*)(row + lane * 4);
  float4 b = *(const float4*)(row + 256 + lane * 4);
  float s = a.x * a.x + a.y * a.y + a.z * a.z + a.w * a.w +
            b.x * b.x + b.y * b.y + b.z * b.z + b.w * b.w;
  #pragma unroll
  for (int off = 1; off < 64; off <<= 1) s += __shfl_xor(s, off);
  const float rn = 1.0f / sqrtf(fmaxf(s, 1e-12f));
  float v[8] = {a.x, a.y, a.z, a.w, b.x, b.y, b.z, b.w};
  #pragma unroll
  for (int h = 0; h < 2; ++h) {
    ushort4 hs, lo;
    #pragma unroll
    for (int q = 0; q < 4; ++q) {
      float x = v[h * 4 + q] * rn;
      unsigned short hb = f2bf(x);
      ((unsigned short*)&hs)[q] = hb;
      ((unsigned short*)&lo)[q] = f2bf(x - bf2f(hb));
    }
    const size_t e = (size_t)m * FDIM + h * 256 + lane * 4;
    *(ushort4*)(Bh + e) = hs;
    *(ushort4*)(Bl + e) = lo;
  }
}

// ---------------- transpose Bh [M][F] -> Bt [F][M] ----------------
__global__ __launch_bounds__(256) void transpose_k(
    const unsigned short* __restrict__ Bh, unsigned short* __restrict__ Bt) {
  __shared__ unsigned short t[32][33];
  const int m0 = blockIdx.x * 32, f0 = blockIdx.y * 32;
  const int tx = threadIdx.x & 31, ty = threadIdx.x >> 5;
  #pragma unroll
  for (int r = ty; r < 32; r += 8)
    t[r][tx] = Bh[(size_t)(m0 + r) * FDIM + f0 + tx];
  __syncthreads();
  #pragma unroll
  for (int r = ty; r < 32; r += 8)
    Bt[(size_t)(f0 + r) * MDIM + m0 + tx] = t[tx][r];
}

// ---------------- input row inv-norms (f32) ----------------
__global__ __launch_bounds__(256) void input_norms_k(
    const float* __restrict__ inp, float* __restrict__ inv_n) {
  const int row = blockIdx.x * 4 + (threadIdx.x >> 6);
  const int lane = threadIdx.x & 63;
  const float* x = inp + (size_t)row * FDIM;
  float4 a = *(const float4*)(x + lane * 4);
  float4 b = *(const float4*)(x + 256 + lane * 4);
  float s = a.x * a.x + a.y * a.y + a.z * a.z + a.w * a.w +
            b.x * b.x + b.y * b.y + b.z * b.z + b.w * b.w;
  #pragma unroll
  for (int off = 1; off < 64; off <<= 1) s += __shfl_xor(s, off);
  if (lane == 0) inv_n[row] = 1.0f / sqrtf(fmaxf(s, 1e-12f));
}

// ---------------- inputs_norm chunk -> bf16 (hi only) ----------------
__global__ __launch_bounds__(256) void prep_a_k(
    const float* __restrict__ inp, const float* __restrict__ inv_n,
    unsigned short* __restrict__ Ah, int baseRow) {
  const size_t q4 = (size_t)blockIdx.x * 256 + threadIdx.x;
  const size_t e = q4 * 4;
  const int lrow = (int)(e >> 9);
  const float rn = inv_n[baseRow + lrow];
  float4 x = *(const float4*)(inp + (size_t)(baseRow + lrow) * FDIM + (e & 511));
  ushort4 hs;
  hs.x = f2bf(x.x * rn); hs.y = f2bf(x.y * rn);
  hs.z = f2bf(x.z * rn); hs.w = f2bf(x.w * rn);
  *(ushort4*)(Ah + e) = hs;
}

// ---------------- GEMM: C[M][N] = A[M][K] * B[N][K]^T, fp32 C ----------------
// Reg-staged LDS (round-4 proven). SPLIT: hi/lo bf16 compensation (3 MFMA).
// qlimit: optional device row-count; blocks beyond padded count exit early.
template <bool SPLIT>
__global__ __launch_bounds__(256) void gemm_bt_k(
    const unsigned short* __restrict__ Ah, const unsigned short* __restrict__ Al,
    const unsigned short* __restrict__ Bh, const unsigned short* __restrict__ Bl,
    float* __restrict__ C, int M, int N, int K, const int* __restrict__ qlimit) {
  const int m0 = blockIdx.y * 128, n0 = blockIdx.x * 128;
  if (qlimit) {
    int lim = *qlimit; if (lim > QCAP) lim = QCAP;
    lim = (lim + 127) & ~127;
    if (m0 >= lim) return;
  }
  constexpr int LDT = 40;  // padded row (shorts): conflict-light
  __shared__ alignas(16) unsigned short sAh[128 * LDT];
  __shared__ alignas(16) unsigned short sBh[128 * LDT];
  __shared__ alignas(16) unsigned short sAl[SPLIT ? 128 * LDT : 8];
  __shared__ alignas(16) unsigned short sBl[SPLIT ? 128 * LDT : 8];

  const int tid = threadIdx.x;
  const int lane = tid & 63, wave = tid >> 6;
  const int wr = wave >> 1, wc = wave & 1;
  const int lr = lane & 15, ls = lane >> 4;

  f32x4 acc[4][4] = {};

  const int u0 = tid, u1 = tid + 256;
  const int r0 = u0 >> 2, c0e = (u0 & 3) * 8;
  const int r1 = u1 >> 2, c1e = (u1 & 3) * 8;

  const unsigned short* pAh0 = Ah + (size_t)(m0 + r0) * K + c0e;
  const unsigned short* pAh1 = Ah + (size_t)(m0 + r1) * K + c1e;
  const unsigned short* pBh0 = Bh + (size_t)(n0 + r0) * K + c0e;
  const unsigned short* pBh1 = Bh + (size_t)(n0 + r1) * K + c1e;
  const unsigned short* pAl0 = nullptr; const unsigned short* pAl1 = nullptr;
  const unsigned short* pBl0 = nullptr; const unsigned short* pBl1 = nullptr;

  u16x8 vAh0 = *(const u16x8*)pAh0, vAh1 = *(const u16x8*)pAh1;
  u16x8 vBh0 = *(const u16x8*)pBh0, vBh1 = *(const u16x8*)pBh1;
  u16x8 vAl0 = {}, vAl1 = {}, vBl0 = {}, vBl1 = {};
  if constexpr (SPLIT) {
    pAl0 = Al + (size_t)(m0 + r0) * K + c0e;
    pAl1 = Al + (size_t)(m0 + r1) * K + c1e;
    pBl0 = Bl + (size_t)(n0 + r0) * K + c0e;
    pBl1 = Bl + (size_t)(n0 + r1) * K + c1e;
    vAl0 = *(const u16x8*)pAl0; vAl1 = *(const u16x8*)pAl1;
    vBl0 = *(const u16x8*)pBl0; vBl1 = *(const u16x8*)pBl1;
  }

  const int nk = K >> 5;
  for (int ks = 0; ks < nk; ++ks) {
    *(u16x8*)&sAh[r0 * LDT + c0e] = vAh0;
    *(u16x8*)&sAh[r1 * LDT + c1e] = vAh1;
    *(u16x8*)&sBh[r0 * LDT + c0e] = vBh0;
    *(u16x8*)&sBh[r1 * LDT + c1e] = vBh1;
    if constexpr (SPLIT) {
      *(u16x8*)&sAl[r0 * LDT + c0e] = vAl0;
      *(u16x8*)&sAl[r1 * LDT + c1e] = vAl1;
      *(u16x8*)&sBl[r0 * LDT + c0e] = vBl0;
      *(u16x8*)&sBl[r1 * LDT + c1e] = vBl1;
    }
    __syncthreads();
    if (ks + 1 < nk) {  // prefetch next K-step into regs (overlaps MFMA below)
      pAh0 += 32; pAh1 += 32; pBh0 += 32; pBh1 += 32;
      vAh0 = *(const u16x8*)pAh0; vAh1 = *(const u16x8*)pAh1;
      vBh0 = *(const u16x8*)pBh0; vBh1 = *(const u16x8*)pBh1;
      if constexpr (SPLIT) {
        pAl0 += 32; pAl1 += 32; pBl0 += 32; pBl1 += 32;
        vAl0 = *(const u16x8*)pAl0; vAl1 = *(const u16x8*)pAl1;
        vBl0 = *(const u16x8*)pBl0; vBl1 = *(const u16x8*)pBl1;
      }
    }
    u16x8 fa[4], fb[4], fal[4], fbl[4];
    #pragma unroll
    for (int i = 0; i < 4; ++i) {
      fa[i] = *(const u16x8*)&sAh[(wr * 64 + i * 16 + lr) * LDT + ls * 8];
      fb[i] = *(const u16x8*)&sBh[(wc * 64 + i * 16 + lr) * LDT + ls * 8];
      if constexpr (SPLIT) {
        fal[i] = *(const u16x8*)&sAl[(wr * 64 + i * 16 + lr) * LDT + ls * 8];
        fbl[i] = *(const u16x8*)&sBl[(wc * 64 + i * 16 + lr) * LDT + ls * 8];
      }
    }
    #pragma unroll
    for (int i = 0; i < 4; ++i)
      #pragma unroll
      for (int j = 0; j < 4; ++j) {
        acc[i][j] = mfma16(fa[i], fb[j], acc[i][j]);
        if constexpr (SPLIT) {
          acc[i][j] = mfma16(fal[i], fb[j], acc[i][j]);
          acc[i][j] = mfma16(fa[i], fbl[j], acc[i][j]);
        }
      }
    __syncthreads();
  }

  #pragma unroll
  for (int i = 0; i < 4; ++i) {
    const int rrow = m0 + wr * 64 + i * 16 + ls * 4;
    #pragma unroll
    for (int j = 0; j < 4; ++j) {
      const int col = n0 + wc * 64 + j * 16 + lr;
      #pragma unroll
      for (int q = 0; q < 4; ++q)
        C[(size_t)(rrow + q) * N + col] = acc[i][j][q];
    }
  }
}

// -------- row softmax + top-2 + P(bf16) + scatter / queue ambiguous --------
__global__ __launch_bounds__(256) void softmax_scatter_k(
    const float* __restrict__ S, unsigned short* __restrict__ P,
    const float* __restrict__ inp, const float* __restrict__ inv_n,
    float* __restrict__ updates, int* __restrict__ queue,
    int* __restrict__ qcount, int baseRow) {
  const int widx = blockIdx.x * 4 + (threadIdx.x >> 6);
  const int lane = threadIdx.x & 63;
  const float* srow = S + (size_t)widx * MDIM;
  float4 v[8];
  float m1 = -3.4e38f, m2 = -3.4e38f;
  int i1 = 0x7fffffff, i2 = 0x7fffffff;
  #pragma unroll
  for (int i = 0; i < 8; ++i) {
    v[i] = *(const float4*)(srow + i * 256 + lane * 4);
    const float xs[4] = {v[i].x, v[i].y, v[i].z, v[i].w};
    #pragma unroll
    for (int q = 0; q < 4; ++q) {
      const float x = xs[q];
      const int idx = i * 256 + lane * 4 + q;
      if (x > m1 || (x == m1 && idx < i1)) { m2 = m1; i2 = i1; m1 = x; i1 = idx; }
      else if (x > m2 || (x == m2 && idx < i2)) { m2 = x; i2 = idx; }
    }
  }
  #pragma unroll
  for (int off = 1; off < 64; off <<= 1) {  // butterfly top-2 merge
    const float n1 = __shfl_xor(m1, off), n2 = __shfl_xor(m2, off);
    const int j1 = __shfl_xor(i1, off), j2 = __shfl_xor(i2, off);
    if (n1 > m1 || (n1 == m1 && j1 < i1)) {
      if (m1 > n2 || (m1 == n2 && i1 < j2)) { m2 = m1; i2 = i1; }
      else { m2 = n2; i2 = j2; }
      m1 = n1; i1 = j1;
    } else if (n1 > m2 || (n1 == m2 && j1 < i2)) { m2 = n1; i2 = j1; }
  }
  float sum = 0.0f;
  #pragma unroll
  for (int i = 0; i < 8; ++i) {
    v[i].x = __expf(SCALE_F * (v[i].x - m1)); sum += v[i].x;
    v[i].y = __expf(SCALE_F * (v[i].y - m1)); sum += v[i].y;
    v[i].z = __expf(SCALE_F * (v[i].z - m1)); sum += v[i].z;
    v[i].w = __expf(SCALE_F * (v[i].w - m1)); sum += v[i].w;
  }
  #pragma unroll
  for (int off = 1; off < 64; off <<= 1) sum += __shfl_xor(sum, off);
  const float rs = 1.0f / sum;
  #pragma unroll
  for (int i = 0; i < 8; ++i) {
    ushort4 pk;
    pk.x = f2bf(v[i].x * rs); pk.y = f2bf(v[i].y * rs);
    pk.z = f2bf(v[i].z * rs); pk.w = f2bf(v[i].w * rs);
    *(ushort4*)(P + (size_t)widx * MDIM + i * 256 + lane * 4) = pk;
  }
  const int tok = baseRow + widx;
  bool do_scatter = true;
  if (m1 - m2 < TAU_BF) {  // ambiguous at bf16-S noise -> split-GEMM refine
    int slot = 0;
    if (lane == 0) slot = atomicAdd(qcount, 1);
    slot = __shfl(slot, 0);
    if (slot < QCAP) {
      if (lane == 0) queue[slot] = tok;
      do_scatter = false;
    }
  }
  if (do_scatter) {
    const float rn = inv_n[tok];
    const float* xrow = inp + (size_t)tok * FDIM;
    float* urow = updates + (size_t)i1 * FDIM;
    #pragma unroll
    for (int h = 0; h < 2; ++h) {
      float4 xv = *(const float4*)(xrow + h * 256 + lane * 4);
      const int e = h * 256 + lane * 4;
      atomicAdd(&urow[e + 0], xv.x * rn);
      atomicAdd(&urow[e + 1], xv.y * rn);
      atomicAdd(&urow[e + 2], xv.z * rn);
      atomicAdd(&urow[e + 3], xv.w * rn);
    }
  }
}

// ------- gather queued tokens' normalized rows -> compact hi/lo matrix -------
__global__ __launch_bounds__(256) void gather_prep_k(
    const int* __restrict__ queue, const int* __restrict__ qcount,
    const float* __restrict__ inp, const float* __restrict__ inv_n,
    unsigned short* __restrict__ Qh, unsigned short* __restrict__ Ql) {
  const int w = blockIdx.x * 4 + (threadIdx.x >> 6);
  const int lane = threadIdx.x & 63;
  int cnt = *qcount; if (cnt > QCAP) cnt = QCAP;
  if (w >= cnt) return;
  const int tok = queue[w];
  const float rn = inv_n[tok];
  const float* x = inp + (size_t)tok * FDIM;
  #pragma unroll
  for (int h = 0; h < 2; ++h) {
    float4 xv = *(const float4*)(x + h * 256 + lane * 4);
    float vv[4] = {xv.x, xv.y, xv.z, xv.w};
    ushort4 hs, lo;
    #pragma unroll
    for (int q = 0; q < 4; ++q) {
      float v = vv[q] * rn;
      unsigned short hb = f2bf(v);
      ((unsigned short*)&hs)[q] = hb;
      ((unsigned short*)&lo)[q] = f2bf(v - bf2f(hb));
    }
    const size_t e = (size_t)w * FDIM + h * 256 + lane * 4;
    *(ushort4*)(Qh + e) = hs;
    *(ushort4*)(Ql + e) = lo;
  }
}

// ------- level-2: full-row top-2 on split-S; fp64 pair-decide if near-tie -------
__global__ __launch_bounds__(256) void refine2_k(
    const int* __restrict__ queue, const int* __restrict__ qcount,
    const float* __restrict__ Sref, const float* __restrict__ inp,
    const float* __restrict__ mem, const float* __restrict__ inv_n,
    float* __restrict__ updates) {
  const int w = blockIdx.x * 4 + (threadIdx.x >> 6);
  const int lane = threadIdx.x & 63;
  int cnt = *qcount; if (cnt > QCAP) cnt = QCAP;
  if (w >= cnt) return;
  const int tok = queue[w];
  const float* srow = Sref + (size_t)w * MDIM;
  float m1 = -3.4e38f, m2 = -3.4e38f;
  int i1 = 0x7fffffff, i2 = 0x7fffffff;
  #pragma unroll
  for (int i = 0; i < 8; ++i) {
    const float4 vv = *(const float4*)(srow + i * 256 + lane * 4);
    const float xs[4] = {vv.x, vv.y, vv.z, vv.w};
    #pragma unroll
    for (int q = 0; q < 4; ++q) {
      const float x = xs[q];
      const int idx = i * 256 + lane * 4 + q;
      if (x > m1 || (x == m1 && idx < i1)) { m2 = m1; i2 = i1; m1 = x; i1 = idx; }
      else if (x > m2 || (x == m2 && idx < i2)) { m2 = x; i2 = idx; }
    }
  }
  #pragma unroll
  for (int off = 1; off < 64; off <<= 1) {
    const float n1 = __shfl_xor(m1, off), n2 = __shfl_xor(m2, off);
    const int j1 = __shfl_xor(i1, off), j2 = __shfl_xor(i2, off);
    if (n1 > m1 || (n1 == m1 && j1 < i1)) {
      if (m1 > n2 || (m1 == n2 && i1 < j2)) { m2 = m1; i2 = i1; }
      else { m2 = n2; i2 = j2; }
      m1 = n1; i1 = j1;
    } else if (n1 > m2 || (n1 == m2 && j1 < i2)) { m2 = n1; i2 = j1; }
  }
  int pick = i1;
  if (m1 - m2 < TAU_SP) {  // near-tie even at split accuracy -> fp64 decides
    const int a = (i1 < i2) ? i1 : i2, b = (i1 < i2) ? i2 : i1;
    const float* x = inp + (size_t)tok * FDIM;
    const float* ma = mem + (size_t)a * FDIM;
    const float* mb = mem + (size_t)b * FDIM;
    double da = 0, db = 0, na = 0, nb = 0;
    #pragma unroll
    for (int j = 0; j < 8; ++j) {
      const int e = lane * 8 + j;
      const double xv = x[e], av = ma[e], bv = mb[e];
      da += xv * av; na += av * av;
      db += xv * bv; nb += bv * bv;
    }
    #pragma unroll
    for (int off = 1; off < 64; off <<= 1) {
      da += __shfl_xor(da, off); na += __shfl_xor(na, off);
      db += __shfl_xor(db, off); nb += __shfl_xor(nb, off);
    }
    const double d1 = da / sqrt(fmax(na, 1e-12));
    const double d2 = db / sqrt(fmax(nb, 1e-12));
    if (d2 > d1) pick = b;
    else pick = a;                      // includes exact tie: smaller index
  }
  const float rn = inv_n[tok];
  const float* xrow = inp + (size_t)tok * FDIM;
  float* urow = updates + (size_t)pick * FDIM;
  #pragma unroll
  for (int h = 0; h < 2; ++h) {
    float4 xv = *(const float4*)(xrow + h * 256 + lane * 4);
    const int e = h * 256 + lane * 4;
    atomicAdd(&urow[e + 0], xv.x * rn);
    atomicAdd(&urow[e + 1], xv.y * rn);
    atomicAdd(&urow[e + 2], xv.z * rn);
    atomicAdd(&urow[e + 3], xv.w * rn);
  }
}

// ---------------- final blend (fp32 out) ----------------
__global__ __launch_bounds__(256) void final_update_k(
    const float* __restrict__ mem, const float* __restrict__ upd,
    float* __restrict__ out) {
  const size_t i = ((size_t)blockIdx.x * 256 + threadIdx.x) * 4;
  float4 m = *(const float4*)(mem + i);
  float4 u = *(const float4*)(upd + i);
  float4 r;
  r.x = m.x * 0.9f + u.x * 0.1f;
  r.y = m.y * 0.9f + u.y * 0.1f;
  r.z = m.z * 0.9f + u.z * 0.1f;
  r.w = m.w * 0.9f + u.w * 0.1f;
  *(float4*)(out + i) = r;
}

extern "C" void kernel_launch(void* const* d_in, const int* in_sizes, int n_in,
                              void* d_out, int out_size, void* d_ws, size_t ws_size,
                              hipStream_t stream) {
  const float* inputs = (const float*)d_in[0];
  const float* memory = (const float*)d_in[1];
  if (n_in >= 2 && in_sizes[0] != N_TOK * FDIM) {  // order guard
    inputs = (const float*)d_in[1];
    memory = (const float*)d_in[0];
  }
  float* out_mu = (float*)d_out;                       // [N][F] fp32
  float* out_um = out_mu + (size_t)N_TOK * FDIM;       // [M][F] fp32

  char* base = (char*)d_ws;
  size_t off = 0;
  auto take = [&](size_t bytes) -> char* {
    char* p = base + off;
    off = (off + bytes + 255) & ~(size_t)255;
    return p;
  };
  unsigned short* Bh = (unsigned short*)take((size_t)MDIM * FDIM * 2);
  unsigned short* Bl = (unsigned short*)take((size_t)MDIM * FDIM * 2);
  unsigned short* Bt = (unsigned short*)take((size_t)MDIM * FDIM * 2);
  float* inv_n = (float*)take((size_t)N_TOK * 4);
  float* updates = (float*)take((size_t)MDIM * FDIM * 4);
  int* queue = (int*)take((size_t)QCAP * 4);
  int* qcount = (int*)take(256);
  unsigned short* Qh = (unsigned short*)take((size_t)QCAP * FDIM * 2);
  unsigned short* Ql = (unsigned short*)take((size_t)QCAP * FDIM * 2);
  float* Sref = (float*)take((size_t)QCAP * MDIM * 4);
  const size_t fixed = off;

  int chunkT = 8192;  // per-pass token chunk; shrink to fit ws
  while (chunkT > 128 && fixed + (size_t)chunkT * 13312 + 4096 > ws_size)
    chunkT >>= 1;
  if (fixed + (size_t)chunkT * 13312 + 4096 > ws_size) return;  // ws too small

  unsigned short* Ah = (unsigned short*)take((size_t)chunkT * FDIM * 2);
  float* Sbuf = (float*)take((size_t)chunkT * MDIM * 4);
  unsigned short* Pbuf = (unsigned short*)take((size_t)chunkT * MDIM * 2);

  zero_k<<<(MDIM * FDIM / 4) / 256, 256, 0, stream>>>(updates, qcount);
  prep_memory_k<<<MDIM, 64, 0, stream>>>(memory, Bh, Bl);
  transpose_k<<<dim3(MDIM / 32, FDIM / 32), 256, 0, stream>>>(Bh, Bt);
  input_norms_k<<<N_TOK / 4, 256, 0, stream>>>(inputs, inv_n);

  for (int baseRow = 0; baseRow < N_TOK; baseRow += chunkT) {
    prep_a_k<<<chunkT / 2, 256, 0, stream>>>(inputs, inv_n, Ah, baseRow);
    gemm_bt_k<false><<<dim3(MDIM / 128, chunkT / 128), 256, 0, stream>>>(
        Ah, nullptr, Bh, nullptr, Sbuf, chunkT, MDIM, FDIM, nullptr);
    softmax_scatter_k<<<chunkT / 4, 256, 0, stream>>>(
        Sbuf, Pbuf, inputs, inv_n, updates, queue, qcount, baseRow);
    gemm_bt_k<false><<<dim3(FDIM / 128, chunkT / 128), 256, 0, stream>>>(
        Pbuf, nullptr, Bt, nullptr, out_mu + (size_t)baseRow * FDIM,
        chunkT, FDIM, MDIM, nullptr);
  }
  // two-level argmax refine: gather ambiguous rows, split-GEMM, decide
  gather_prep_k<<<QCAP / 4, 256, 0, stream>>>(queue, qcount, inputs, inv_n, Qh, Ql);
  gemm_bt_k<true><<<dim3(MDIM / 128, QCAP / 128), 256, 0, stream>>>(
      Qh, Ql, Bh, Bl, Sref, QCAP, MDIM, FDIM, qcount);
  refine2_k<<<QCAP / 4, 256, 0, stream>>>(queue, qcount, Sref, inputs, memory,
                                          inv_n, updates);
  final_update_k<<<(MDIM * FDIM / 4) / 256, 256, 0, stream>>>(memory, updates, out_um);
}

// Round 7
// 1166.141 us; speedup vs baseline: 1.3768x; 1.0577x over previous
//
#include <hip/hip_runtime.h>
#include <stdint.h>

#define N_TOK   65536
#define MDIM    2048
#define FDIM    512
#define SCALE_F 10.0f
#define TAU_BF  1.2e-3f   // level-1: bf16-S ambiguity (~9 sigma)
#define TAU_SP  2e-5f     // level-2: split-S ambiguity (~100 sigma)
#define QCAP    8192

typedef __attribute__((ext_vector_type(8))) unsigned short u16x8;
typedef __attribute__((ext_vector_type(8))) __bf16 bf16x8;
typedef __attribute__((ext_vector_type(4))) float f32x4;

__device__ __forceinline__ unsigned short f2bf(float f) {
  unsigned int u = __builtin_bit_cast(unsigned int, f);
  u += 0x7fffu + ((u >> 16) & 1u);   // round-to-nearest-even
  return (unsigned short)(u >> 16);
}
__device__ __forceinline__ float bf2f(unsigned short b) {
  return __builtin_bit_cast(float, (unsigned int)b << 16);
}
__device__ __forceinline__ f32x4 mfma16(u16x8 a, u16x8 b, f32x4 c) {
  return __builtin_amdgcn_mfma_f32_16x16x32_bf16(
      __builtin_bit_cast(bf16x8, a), __builtin_bit_cast(bf16x8, b), c, 0, 0, 0);
}
// async global->LDS, 16B per lane; LDS dest = wave-uniform base + lane*16B
__device__ __forceinline__ void gload16(const unsigned short* g, unsigned short* l) {
  __builtin_amdgcn_global_load_lds(
      (const __attribute__((address_space(1))) unsigned int*)g,
      (__attribute__((address_space(3))) unsigned int*)l,
      16, 0, 0);
}

// ---------------- zero updates + queue counter ----------------
__global__ __launch_bounds__(256) void zero_k(float* __restrict__ updates,
                                              int* __restrict__ qcount) {
  const size_t i = ((size_t)blockIdx.x * 256 + threadIdx.x) * 4;
  *(float4*)(updates + i) = make_float4(0.f, 0.f, 0.f, 0.f);
  if (blockIdx.x == 0 && threadIdx.x == 0) *qcount = 0;
}

// ---------------- memory_norm -> bf16 hi/lo ----------------
__global__ __launch_bounds__(64) void prep_memory_k(
    const float* __restrict__ mem, unsigned short* __restrict__ Bh,
    unsigned short* __restrict__ Bl) {
  const int m = blockIdx.x;
  const int lane = threadIdx.x;
  const float* row = mem + (size_t)m * FDIM;
  float4 a = *(const float4*)(row + lane * 4);
  float4 b = *(const float4*)(row + 256 + lane * 4);
  float s = a.x * a.x + a.y * a.y + a.z * a.z + a.w * a.w +
            b.x * b.x + b.y * b.y + b.z * b.z + b.w * b.w;
  #pragma unroll
  for (int off = 1; off < 64; off <<= 1) s += __shfl_xor(s, off);
  const float rn = 1.0f / sqrtf(fmaxf(s, 1e-12f));
  float v[8] = {a.x, a.y, a.z, a.w, b.x, b.y, b.z, b.w};
  #pragma unroll
  for (int h = 0; h < 2; ++h) {
    ushort4 hs, lo;
    #pragma unroll
    for (int q = 0; q < 4; ++q) {
      float x = v[h * 4 + q] * rn;
      unsigned short hb = f2bf(x);
      ((unsigned short*)&hs)[q] = hb;
      ((unsigned short*)&lo)[q] = f2bf(x - bf2f(hb));
    }
    const size_t e = (size_t)m * FDIM + h * 256 + lane * 4;
    *(ushort4*)(Bh + e) = hs;
    *(ushort4*)(Bl + e) = lo;
  }
}

// ---------------- transpose Bh [M][F] -> Bt [F][M] ----------------
__global__ __launch_bounds__(256) void transpose_k(
    const unsigned short* __restrict__ Bh, unsigned short* __restrict__ Bt) {
  __shared__ unsigned short t[32][33];
  const int m0 = blockIdx.x * 32, f0 = blockIdx.y * 32;
  const int tx = threadIdx.x & 31, ty = threadIdx.x >> 5;
  #pragma unroll
  for (int r = ty; r < 32; r += 8)
    t[r][tx] = Bh[(size_t)(m0 + r) * FDIM + f0 + tx];
  __syncthreads();
  #pragma unroll
  for (int r = ty; r < 32; r += 8)
    Bt[(size_t)(f0 + r) * MDIM + m0 + tx] = t[tx][r];
}

// ---------------- input row inv-norms (f32) ----------------
__global__ __launch_bounds__(256) void input_norms_k(
    const float* __restrict__ inp, float* __restrict__ inv_n) {
  const int row = blockIdx.x * 4 + (threadIdx.x >> 6);
  const int lane = threadIdx.x & 63;
  const float* x = inp + (size_t)row * FDIM;
  float4 a = *(const float4*)(x + lane * 4);
  float4 b = *(const float4*)(x + 256 + lane * 4);
  float s = a.x * a.x + a.y * a.y + a.z * a.z + a.w * a.w +
            b.x * b.x + b.y * b.y + b.z * b.z + b.w * b.w;
  #pragma unroll
  for (int off = 1; off < 64; off <<= 1) s += __shfl_xor(s, off);
  if (lane == 0) inv_n[row] = 1.0f / sqrtf(fmaxf(s, 1e-12f));
}

// ---------------- inputs_norm chunk -> bf16 (hi only) ----------------
__global__ __launch_bounds__(256) void prep_a_k(
    const float* __restrict__ inp, const float* __restrict__ inv_n,
    unsigned short* __restrict__ Ah, int baseRow) {
  const size_t q4 = (size_t)blockIdx.x * 256 + threadIdx.x;
  const size_t e = q4 * 4;
  const int lrow = (int)(e >> 9);
  const float rn = inv_n[baseRow + lrow];
  float4 x = *(const float4*)(inp + (size_t)(baseRow + lrow) * FDIM + (e & 511));
  ushort4 hs;
  hs.x = f2bf(x.x * rn); hs.y = f2bf(x.y * rn);
  hs.z = f2bf(x.z * rn); hs.w = f2bf(x.w * rn);
  *(ushort4*)(Ah + e) = hs;
}

// ---------------- GEMM: C[M][N] = A[M][K] * B[N][K]^T, fp32 C ----------------
// m97 structure: linear LDS [128][32] shorts, global_load_lds 16B staging,
// 2-barrier K-loop. 1D grid, optional bijective XCD swizzle (nwg%8==0).
// SPLIT: hi/lo bf16 compensation (3 MFMA). qlimit: device row-count gate.
template <bool SPLIT, bool SWZ>
__global__ __launch_bounds__(256) void gemm_bt_k(
    const unsigned short* __restrict__ Ah, const unsigned short* __restrict__ Al,
    const unsigned short* __restrict__ Bh, const unsigned short* __restrict__ Bl,
    float* __restrict__ C, int N, int K, int nbxLog2,
    const int* __restrict__ qlimit) {
  int wg = blockIdx.x;
  if (SWZ) {  // bijective: nwg % 8 == 0 guaranteed by launcher
    const int q = gridDim.x >> 3;
    wg = (wg & 7) * q + (wg >> 3);
  }
  const int bx = wg & ((1 << nbxLog2) - 1);
  const int by = wg >> nbxLog2;
  const int m0 = by * 128, n0 = bx * 128;
  if (qlimit) {
    int lim = *qlimit; if (lim > QCAP) lim = QCAP;
    lim = (lim + 127) & ~127;
    if (m0 >= lim) return;
  }
  __shared__ alignas(16) unsigned short sAh[128 * 32];
  __shared__ alignas(16) unsigned short sBh[128 * 32];
  __shared__ alignas(16) unsigned short sAl[SPLIT ? 128 * 32 : 8];
  __shared__ alignas(16) unsigned short sBl[SPLIT ? 128 * 32 : 8];

  const int tid = threadIdx.x;
  const int lane = tid & 63, wave = tid >> 6;
  const int wr = wave >> 1, wc = wave & 1;
  const int lr = lane & 15, ls = lane >> 4;

  f32x4 acc[4][4] = {};

  // staging map (linear): wave w covers rows [w*32, w*32+32); two issues of
  // 16 rows each; lane -> row += lane>>2, 16B col-slot = lane&3.
  const int row0 = wave * 32 + (lane >> 2);
  const int row1 = row0 + 16;
  const int ce = (lane & 3) * 8;
  const unsigned short* gA0 = Ah + (size_t)(m0 + row0) * K + ce;
  const unsigned short* gA1 = Ah + (size_t)(m0 + row1) * K + ce;
  const unsigned short* gB0 = Bh + (size_t)(n0 + row0) * K + ce;
  const unsigned short* gB1 = Bh + (size_t)(n0 + row1) * K + ce;
  const unsigned short* gAl0 = nullptr; const unsigned short* gAl1 = nullptr;
  const unsigned short* gBl0 = nullptr; const unsigned short* gBl1 = nullptr;
  if constexpr (SPLIT) {
    gAl0 = Al + (size_t)(m0 + row0) * K + ce;
    gAl1 = Al + (size_t)(m0 + row1) * K + ce;
    gBl0 = Bl + (size_t)(n0 + row0) * K + ce;
    gBl1 = Bl + (size_t)(n0 + row1) * K + ce;
  }
  unsigned short* lA0 = &sAh[wave * 1024];
  unsigned short* lA1 = &sAh[wave * 1024 + 512];
  unsigned short* lB0 = &sBh[wave * 1024];
  unsigned short* lB1 = &sBh[wave * 1024 + 512];
  unsigned short* lAl0 = SPLIT ? &sAl[wave * 1024] : nullptr;
  unsigned short* lAl1 = SPLIT ? &sAl[wave * 1024 + 512] : nullptr;
  unsigned short* lBl0 = SPLIT ? &sBl[wave * 1024] : nullptr;
  unsigned short* lBl1 = SPLIT ? &sBl[wave * 1024 + 512] : nullptr;

  const int nk = K >> 5;
  for (int ks = 0; ks < nk; ++ks) {
    gload16(gA0, lA0); gload16(gA1, lA1);
    gload16(gB0, lB0); gload16(gB1, lB1);
    if constexpr (SPLIT) {
      gload16(gAl0, lAl0); gload16(gAl1, lAl1);
      gload16(gBl0, lBl0); gload16(gBl1, lBl1);
    }
    gA0 += 32; gA1 += 32; gB0 += 32; gB1 += 32;
    if constexpr (SPLIT) { gAl0 += 32; gAl1 += 32; gBl0 += 32; gBl1 += 32; }
    __syncthreads();  // drains vmcnt -> staged data visible

    u16x8 fa[4], fb[4], fal[4], fbl[4];
    #pragma unroll
    for (int i = 0; i < 4; ++i) {
      const int ra = (wr * 64 + i * 16 + lr) * 32 + ls * 8;
      const int rb = (wc * 64 + i * 16 + lr) * 32 + ls * 8;
      fa[i] = *(const u16x8*)&sAh[ra];
      fb[i] = *(const u16x8*)&sBh[rb];
      if constexpr (SPLIT) {
        fal[i] = *(const u16x8*)&sAl[ra];
        fbl[i] = *(const u16x8*)&sBl[rb];
      }
    }
    #pragma unroll
    for (int i = 0; i < 4; ++i)
      #pragma unroll
      for (int j = 0; j < 4; ++j) {
        acc[i][j] = mfma16(fa[i], fb[j], acc[i][j]);
        if constexpr (SPLIT) {
          acc[i][j] = mfma16(fal[i], fb[j], acc[i][j]);
          acc[i][j] = mfma16(fa[i], fbl[j], acc[i][j]);
        }
      }
    __syncthreads();  // protect LDS before next overwrite
  }

  #pragma unroll
  for (int i = 0; i < 4; ++i) {
    const int rrow = m0 + wr * 64 + i * 16 + ls * 4;
    #pragma unroll
    for (int j = 0; j < 4; ++j) {
      const int col = n0 + wc * 64 + j * 16 + lr;
      #pragma unroll
      for (int q = 0; q < 4; ++q)
        C[(size_t)(rrow + q) * N + col] = acc[i][j][q];
    }
  }
}

// -------- row softmax + top-2 + P(bf16) + scatter / queue ambiguous --------
__global__ __launch_bounds__(256) void softmax_scatter_k(
    const float* __restrict__ S, unsigned short* __restrict__ P,
    const float* __restrict__ inp, const float* __restrict__ inv_n,
    float* __restrict__ updates, int* __restrict__ queue,
    int* __restrict__ qcount, int baseRow) {
  const int widx = blockIdx.x * 4 + (threadIdx.x >> 6);
  const int lane = threadIdx.x & 63;
  const float* srow = S + (size_t)widx * MDIM;
  float4 v[8];
  float m1 = -3.4e38f, m2 = -3.4e38f;
  int i1 = 0x7fffffff, i2 = 0x7fffffff;
  #pragma unroll
  for (int i = 0; i < 8; ++i) {
    v[i] = *(const float4*)(srow + i * 256 + lane * 4);
    const float xs[4] = {v[i].x, v[i].y, v[i].z, v[i].w};
    #pragma unroll
    for (int q = 0; q < 4; ++q) {
      const float x = xs[q];
      const int idx = i * 256 + lane * 4 + q;
      if (x > m1 || (x == m1 && idx < i1)) { m2 = m1; i2 = i1; m1 = x; i1 = idx; }
      else if (x > m2 || (x == m2 && idx < i2)) { m2 = x; i2 = idx; }
    }
  }
  #pragma unroll
  for (int off = 1; off < 64; off <<= 1) {  // butterfly top-2 merge
    const float n1 = __shfl_xor(m1, off), n2 = __shfl_xor(m2, off);
    const int j1 = __shfl_xor(i1, off), j2 = __shfl_xor(i2, off);
    if (n1 > m1 || (n1 == m1 && j1 < i1)) {
      if (m1 > n2 || (m1 == n2 && i1 < j2)) { m2 = m1; i2 = i1; }
      else { m2 = n2; i2 = j2; }
      m1 = n1; i1 = j1;
    } else if (n1 > m2 || (n1 == m2 && j1 < i2)) { m2 = n1; i2 = j1; }
  }
  float sum = 0.0f;
  #pragma unroll
  for (int i = 0; i < 8; ++i) {
    v[i].x = __expf(SCALE_F * (v[i].x - m1)); sum += v[i].x;
    v[i].y = __expf(SCALE_F * (v[i].y - m1)); sum += v[i].y;
    v[i].z = __expf(SCALE_F * (v[i].z - m1)); sum += v[i].z;
    v[i].w = __expf(SCALE_F * (v[i].w - m1)); sum += v[i].w;
  }
  #pragma unroll
  for (int off = 1; off < 64; off <<= 1) sum += __shfl_xor(sum, off);
  const float rs = 1.0f / sum;
  #pragma unroll
  for (int i = 0; i < 8; ++i) {
    ushort4 pk;
    pk.x = f2bf(v[i].x * rs); pk.y = f2bf(v[i].y * rs);
    pk.z = f2bf(v[i].z * rs); pk.w = f2bf(v[i].w * rs);
    *(ushort4*)(P + (size_t)widx * MDIM + i * 256 + lane * 4) = pk;
  }
  const int tok = baseRow + widx;
  bool do_scatter = true;
  if (m1 - m2 < TAU_BF) {  // ambiguous at bf16-S noise -> split-GEMM refine
    int slot = 0;
    if (lane == 0) slot = atomicAdd(qcount, 1);
    slot = __shfl(slot, 0);
    if (slot < QCAP) {
      if (lane == 0) queue[slot] = tok;
      do_scatter = false;
    }
  }
  if (do_scatter) {
    const float rn = inv_n[tok];
    const float* xrow = inp + (size_t)tok * FDIM;
    float* urow = updates + (size_t)i1 * FDIM;
    #pragma unroll
    for (int h = 0; h < 2; ++h) {
      float4 xv = *(const float4*)(xrow + h * 256 + lane * 4);
      const int e = h * 256 + lane * 4;
      atomicAdd(&urow[e + 0], xv.x * rn);
      atomicAdd(&urow[e + 1], xv.y * rn);
      atomicAdd(&urow[e + 2], xv.z * rn);
      atomicAdd(&urow[e + 3], xv.w * rn);
    }
  }
}

// ------- gather queued tokens' normalized rows -> compact hi/lo matrix -------
__global__ __launch_bounds__(256) void gather_prep_k(
    const int* __restrict__ queue, const int* __restrict__ qcount,
    const float* __restrict__ inp, const float* __restrict__ inv_n,
    unsigned short* __restrict__ Qh, unsigned short* __restrict__ Ql) {
  const int w = blockIdx.x * 4 + (threadIdx.x >> 6);
  const int lane = threadIdx.x & 63;
  int cnt = *qcount; if (cnt > QCAP) cnt = QCAP;
  if (w >= cnt) return;
  const int tok = queue[w];
  const float rn = inv_n[tok];
  const float* x = inp + (size_t)tok * FDIM;
  #pragma unroll
  for (int h = 0; h < 2; ++h) {
    float4 xv = *(const float4*)(x + h * 256 + lane * 4);
    float vv[4] = {xv.x, xv.y, xv.z, xv.w};
    ushort4 hs, lo;
    #pragma unroll
    for (int q = 0; q < 4; ++q) {
      float v = vv[q] * rn;
      unsigned short hb = f2bf(v);
      ((unsigned short*)&hs)[q] = hb;
      ((unsigned short*)&lo)[q] = f2bf(v - bf2f(hb));
    }
    const size_t e = (size_t)w * FDIM + h * 256 + lane * 4;
    *(ushort4*)(Qh + e) = hs;
    *(ushort4*)(Ql + e) = lo;
  }
}

// ------- level-2: full-row top-2 on split-S; fp64 pair-decide if near-tie -------
__global__ __launch_bounds__(256) void refine2_k(
    const int* __restrict__ queue, const int* __restrict__ qcount,
    const float* __restrict__ Sref, const float* __restrict__ inp,
    const float* __restrict__ mem, const float* __restrict__ inv_n,
    float* __restrict__ updates) {
  const int w = blockIdx.x * 4 + (threadIdx.x >> 6);
  const int lane = threadIdx.x & 63;
  int cnt = *qcount; if (cnt > QCAP) cnt = QCAP;
  if (w >= cnt) return;
  const int tok = queue[w];
  const float* srow = Sref + (size_t)w * MDIM;
  float m1 = -3.4e38f, m2 = -3.4e38f;
  int i1 = 0x7fffffff, i2 = 0x7fffffff;
  #pragma unroll
  for (int i = 0; i < 8; ++i) {
    const float4 vv = *(const float4*)(srow + i * 256 + lane * 4);
    const float xs[4] = {vv.x, vv.y, vv.z, vv.w};
    #pragma unroll
    for (int q = 0; q < 4; ++q) {
      const float x = xs[q];
      const int idx = i * 256 + lane * 4 + q;
      if (x > m1 || (x == m1 && idx < i1)) { m2 = m1; i2 = i1; m1 = x; i1 = idx; }
      else if (x > m2 || (x == m2 && idx < i2)) { m2 = x; i2 = idx; }
    }
  }
  #pragma unroll
  for (int off = 1; off < 64; off <<= 1) {
    const float n1 = __shfl_xor(m1, off), n2 = __shfl_xor(m2, off);
    const int j1 = __shfl_xor(i1, off), j2 = __shfl_xor(i2, off);
    if (n1 > m1 || (n1 == m1 && j1 < i1)) {
      if (m1 > n2 || (m1 == n2 && i1 < j2)) { m2 = m1; i2 = i1; }
      else { m2 = n2; i2 = j2; }
      m1 = n1; i1 = j1;
    } else if (n1 > m2 || (n1 == m2 && j1 < i2)) { m2 = n1; i2 = j1; }
  }
  int pick = i1;
  if (m1 - m2 < TAU_SP) {  // near-tie even at split accuracy -> fp64 decides
    const int a = (i1 < i2) ? i1 : i2, b = (i1 < i2) ? i2 : i1;
    const float* x = inp + (size_t)tok * FDIM;
    const float* ma = mem + (size_t)a * FDIM;
    const float* mb = mem + (size_t)b * FDIM;
    double da = 0, db = 0, na = 0, nb = 0;
    #pragma unroll
    for (int j = 0; j < 8; ++j) {
      const int e = lane * 8 + j;
      const double xv = x[e], av = ma[e], bv = mb[e];
      da += xv * av; na += av * av;
      db += xv * bv; nb += bv * bv;
    }
    #pragma unroll
    for (int off = 1; off < 64; off <<= 1) {
      da += __shfl_xor(da, off); na += __shfl_xor(na, off);
      db += __shfl_xor(db, off); nb += __shfl_xor(nb, off);
    }
    const double d1 = da / sqrt(fmax(na, 1e-12));
    const double d2 = db / sqrt(fmax(nb, 1e-12));
    if (d2 > d1) pick = b;
    else pick = a;                      // includes exact tie: smaller index
  }
  const float rn = inv_n[tok];
  const float* xrow = inp + (size_t)tok * FDIM;
  float* urow = updates + (size_t)pick * FDIM;
  #pragma unroll
  for (int h = 0; h < 2; ++h) {
    float4 xv = *(const float4*)(xrow + h * 256 + lane * 4);
    const int e = h * 256 + lane * 4;
    atomicAdd(&urow[e + 0], xv.x * rn);
    atomicAdd(&urow[e + 1], xv.y * rn);
    atomicAdd(&urow[e + 2], xv.z * rn);
    atomicAdd(&urow[e + 3], xv.w * rn);
  }
}

// ---------------- final blend (fp32 out) ----------------
__global__ __launch_bounds__(256) void final_update_k(
    const float* __restrict__ mem, const float* __restrict__ upd,
    float* __restrict__ out) {
  const size_t i = ((size_t)blockIdx.x * 256 + threadIdx.x) * 4;
  float4 m = *(const float4*)(mem + i);
  float4 u = *(const float4*)(upd + i);
  float4 r;
  r.x = m.x * 0.9f + u.x * 0.1f;
  r.y = m.y * 0.9f + u.y * 0.1f;
  r.z = m.z * 0.9f + u.z * 0.1f;
  r.w = m.w * 0.9f + u.w * 0.1f;
  *(float4*)(out + i) = r;
}

extern "C" void kernel_launch(void* const* d_in, const int* in_sizes, int n_in,
                              void* d_out, int out_size, void* d_ws, size_t ws_size,
                              hipStream_t stream) {
  const float* inputs = (const float*)d_in[0];
  const float* memory = (const float*)d_in[1];
  if (n_in >= 2 && in_sizes[0] != N_TOK * FDIM) {  // order guard
    inputs = (const float*)d_in[1];
    memory = (const float*)d_in[0];
  }
  float* out_mu = (float*)d_out;                       // [N][F] fp32
  float* out_um = out_mu + (size_t)N_TOK * FDIM;       // [M][F] fp32

  char* base = (char*)d_ws;
  size_t off = 0;
  auto take = [&](size_t bytes) -> char* {
    char* p = base + off;
    off = (off + bytes + 255) & ~(size_t)255;
    return p;
  };
  unsigned short* Bh = (unsigned short*)take((size_t)MDIM * FDIM * 2);
  unsigned short* Bl = (unsigned short*)take((size_t)MDIM * FDIM * 2);
  unsigned short* Bt = (unsigned short*)take((size_t)MDIM * FDIM * 2);
  float* inv_n = (float*)take((size_t)N_TOK * 4);
  float* updates = (float*)take((size_t)MDIM * FDIM * 4);
  int* queue = (int*)take((size_t)QCAP * 4);
  int* qcount = (int*)take(256);
  unsigned short* Qh = (unsigned short*)take((size_t)QCAP * FDIM * 2);
  unsigned short* Ql = (unsigned short*)take((size_t)QCAP * FDIM * 2);
  float* Sref = (float*)take((size_t)QCAP * MDIM * 4);
  const size_t fixed = off;

  int chunkT = 16384;  // per-pass token chunk; shrink to fit ws
  while (chunkT > 128 && fixed + (size_t)chunkT * 13312 + 4096 > ws_size)
    chunkT >>= 1;
  if (fixed + (size_t)chunkT * 13312 + 4096 > ws_size) return;  // ws too small

  unsigned short* Ah = (unsigned short*)take((size_t)chunkT * FDIM * 2);
  float* Sbuf = (float*)take((size_t)chunkT * MDIM * 4);
  unsigned short* Pbuf = (unsigned short*)take((size_t)chunkT * MDIM * 2);

  zero_k<<<(MDIM * FDIM / 4) / 256, 256, 0, stream>>>(updates, qcount);
  prep_memory_k<<<MDIM, 64, 0, stream>>>(memory, Bh, Bl);
  transpose_k<<<dim3(MDIM / 32, FDIM / 32), 256, 0, stream>>>(Bh, Bt);
  input_norms_k<<<N_TOK / 4, 256, 0, stream>>>(inputs, inv_n);

  const int nby = chunkT / 128;
  for (int baseRow = 0; baseRow < N_TOK; baseRow += chunkT) {
    prep_a_k<<<chunkT / 2, 256, 0, stream>>>(inputs, inv_n, Ah, baseRow);
    // GEMM1: S = Anorm * Bnorm^T  (nbx=16 -> log2=4; nwg = 16*nby, %8==0)
    gemm_bt_k<false, true><<<16 * nby, 256, 0, stream>>>(
        Ah, nullptr, Bh, nullptr, Sbuf, MDIM, FDIM, 4, nullptr);
    softmax_scatter_k<<<chunkT / 4, 256, 0, stream>>>(
        Sbuf, Pbuf, inputs, inv_n, updates, queue, qcount, baseRow);
    // GEMM2: out = P * Bt^T  (nbx=4 -> log2=2; nwg = 4*nby, %8==0)
    gemm_bt_k<false, true><<<4 * nby, 256, 0, stream>>>(
        Pbuf, nullptr, Bt, nullptr, out_mu + (size_t)baseRow * FDIM,
        FDIM, MDIM, 2, nullptr);
  }
  // two-level argmax refine: gather ambiguous rows, split-GEMM, decide
  gather_prep_k<<<QCAP / 4, 256, 0, stream>>>(queue, qcount, inputs, inv_n, Qh, Ql);
  gemm_bt_k<true, false><<<16 * (QCAP / 128), 256, 0, stream>>>(
      Qh, Ql, Bh, Bl, Sref, MDIM, FDIM, 4, qcount);
  refine2_k<<<QCAP / 4, 256, 0, stream>>>(queue, qcount, Sref, inputs, memory,
                                          inv_n, updates);
  final_update_k<<<(MDIM * FDIM / 4) / 256, 256, 0, stream>>>(memory, updates, out_um);
}

// Round 8
// 854.210 us; speedup vs baseline: 1.8795x; 1.3652x over previous
//
#include <hip/hip_runtime.h>
#include <stdint.h>

#define N_TOK   65536
#define MDIM    2048
#define FDIM    512
#define SCALE_F 10.0f
#define TAU_BF  1.2e-3f   // level-1: bf16-S ambiguity (~9 sigma)
#define TAU_SP  2e-5f     // level-2: split-S ambiguity (~100 sigma)
#define QCAP    8192

typedef __attribute__((ext_vector_type(8))) unsigned short u16x8;
typedef __attribute__((ext_vector_type(8))) __bf16 bf16x8;
typedef __attribute__((ext_vector_type(4))) float f32x4;

__device__ __forceinline__ unsigned short f2bf(float f) {
  unsigned int u = __builtin_bit_cast(unsigned int, f);
  u += 0x7fffu + ((u >> 16) & 1u);   // round-to-nearest-even
  return (unsigned short)(u >> 16);
}
__device__ __forceinline__ float bf2f(unsigned short b) {
  return __builtin_bit_cast(float, (unsigned int)b << 16);
}
__device__ __forceinline__ f32x4 mfma16(u16x8 a, u16x8 b, f32x4 c) {
  return __builtin_amdgcn_mfma_f32_16x16x32_bf16(
      __builtin_bit_cast(bf16x8, a), __builtin_bit_cast(bf16x8, b), c, 0, 0, 0);
}
// async global->LDS, 16B per lane; LDS dest = wave-uniform base + lane*16B
__device__ __forceinline__ void gload16(const unsigned short* g, unsigned short* l) {
  __builtin_amdgcn_global_load_lds(
      (const __attribute__((address_space(1))) unsigned int*)g,
      (__attribute__((address_space(3))) unsigned int*)l,
      16, 0, 0);
}

// ---------------- zero queue counter ----------------
__global__ __launch_bounds__(64) void zero_k(int* __restrict__ qcount) {
  if (threadIdx.x == 0) *qcount = 0;
}

// ---------------- memory_norm -> bf16 hi/lo ----------------
__global__ __launch_bounds__(64) void prep_memory_k(
    const float* __restrict__ mem, unsigned short* __restrict__ Bh,
    unsigned short* __restrict__ Bl) {
  const int m = blockIdx.x;
  const int lane = threadIdx.x;
  const float* row = mem + (size_t)m * FDIM;
  float4 a = *(const float4*)(row + lane * 4);
  float4 b = *(const float4*)(row + 256 + lane * 4);
  float s = a.x * a.x + a.y * a.y + a.z * a.z + a.w * a.w +
            b.x * b.x + b.y * b.y + b.z * b.z + b.w * b.w;
  #pragma unroll
  for (int off = 1; off < 64; off <<= 1) s += __shfl_xor(s, off);
  const float rn = 1.0f / sqrtf(fmaxf(s, 1e-12f));
  float v[8] = {a.x, a.y, a.z, a.w, b.x, b.y, b.z, b.w};
  #pragma unroll
  for (int h = 0; h < 2; ++h) {
    ushort4 hs, lo;
    #pragma unroll
    for (int q = 0; q < 4; ++q) {
      float x = v[h * 4 + q] * rn;
      unsigned short hb = f2bf(x);
      ((unsigned short*)&hs)[q] = hb;
      ((unsigned short*)&lo)[q] = f2bf(x - bf2f(hb));
    }
    const size_t e = (size_t)m * FDIM + h * 256 + lane * 4;
    *(ushort4*)(Bh + e) = hs;
    *(ushort4*)(Bl + e) = lo;
  }
}

// ---------------- transpose Bh [M][F] -> Bt [F][M] ----------------
__global__ __launch_bounds__(256) void transpose_k(
    const unsigned short* __restrict__ Bh, unsigned short* __restrict__ Bt) {
  __shared__ unsigned short t[32][33];
  const int m0 = blockIdx.x * 32, f0 = blockIdx.y * 32;
  const int tx = threadIdx.x & 31, ty = threadIdx.x >> 5;
  #pragma unroll
  for (int r = ty; r < 32; r += 8)
    t[r][tx] = Bh[(size_t)(m0 + r) * FDIM + f0 + tx];
  __syncthreads();
  #pragma unroll
  for (int r = ty; r < 32; r += 8)
    Bt[(size_t)(f0 + r) * MDIM + m0 + tx] = t[tx][r];
}

// ---------------- input row inv-norms (f32) ----------------
__global__ __launch_bounds__(256) void input_norms_k(
    const float* __restrict__ inp, float* __restrict__ inv_n) {
  const int row = blockIdx.x * 4 + (threadIdx.x >> 6);
  const int lane = threadIdx.x & 63;
  const float* x = inp + (size_t)row * FDIM;
  float4 a = *(const float4*)(x + lane * 4);
  float4 b = *(const float4*)(x + 256 + lane * 4);
  float s = a.x * a.x + a.y * a.y + a.z * a.z + a.w * a.w +
            b.x * b.x + b.y * b.y + b.z * b.z + b.w * b.w;
  #pragma unroll
  for (int off = 1; off < 64; off <<= 1) s += __shfl_xor(s, off);
  if (lane == 0) inv_n[row] = 1.0f / sqrtf(fmaxf(s, 1e-12f));
}

// ---------------- inputs_norm chunk -> bf16 (hi only) ----------------
__global__ __launch_bounds__(256) void prep_a_k(
    const float* __restrict__ inp, const float* __restrict__ inv_n,
    unsigned short* __restrict__ Ah, int baseRow) {
  const size_t q4 = (size_t)blockIdx.x * 256 + threadIdx.x;
  const size_t e = q4 * 4;
  const int lrow = (int)(e >> 9);
  const float rn = inv_n[baseRow + lrow];
  float4 x = *(const float4*)(inp + (size_t)(baseRow + lrow) * FDIM + (e & 511));
  ushort4 hs;
  hs.x = f2bf(x.x * rn); hs.y = f2bf(x.y * rn);
  hs.z = f2bf(x.z * rn); hs.w = f2bf(x.w * rn);
  *(ushort4*)(Ah + e) = hs;
}

// ---------------- GEMM: C[M][N] = A[M][K] * B[N][K]^T, fp32 C ----------------
// m97 structure: linear LDS [128][32] shorts, global_load_lds 16B staging,
// 2-barrier K-loop. 1D grid, optional bijective XCD swizzle (nwg%8==0).
template <bool SPLIT, bool SWZ>
__global__ __launch_bounds__(256) void gemm_bt_k(
    const unsigned short* __restrict__ Ah, const unsigned short* __restrict__ Al,
    const unsigned short* __restrict__ Bh, const unsigned short* __restrict__ Bl,
    float* __restrict__ C, int N, int K, int nbxLog2,
    const int* __restrict__ qlimit) {
  int wg = blockIdx.x;
  if (SWZ) {  // bijective: nwg % 8 == 0 guaranteed by launcher
    const int q = gridDim.x >> 3;
    wg = (wg & 7) * q + (wg >> 3);
  }
  const int bx = wg & ((1 << nbxLog2) - 1);
  const int by = wg >> nbxLog2;
  const int m0 = by * 128, n0 = bx * 128;
  if (qlimit) {
    int lim = *qlimit; if (lim > QCAP) lim = QCAP;
    lim = (lim + 127) & ~127;
    if (m0 >= lim) return;
  }
  __shared__ alignas(16) unsigned short sAh[128 * 32];
  __shared__ alignas(16) unsigned short sBh[128 * 32];
  __shared__ alignas(16) unsigned short sAl[SPLIT ? 128 * 32 : 8];
  __shared__ alignas(16) unsigned short sBl[SPLIT ? 128 * 32 : 8];

  const int tid = threadIdx.x;
  const int lane = tid & 63, wave = tid >> 6;
  const int wr = wave >> 1, wc = wave & 1;
  const int lr = lane & 15, ls = lane >> 4;

  f32x4 acc[4][4] = {};

  const int row0 = wave * 32 + (lane >> 2);
  const int row1 = row0 + 16;
  const int ce = (lane & 3) * 8;
  const unsigned short* gA0 = Ah + (size_t)(m0 + row0) * K + ce;
  const unsigned short* gA1 = Ah + (size_t)(m0 + row1) * K + ce;
  const unsigned short* gB0 = Bh + (size_t)(n0 + row0) * K + ce;
  const unsigned short* gB1 = Bh + (size_t)(n0 + row1) * K + ce;
  const unsigned short* gAl0 = nullptr; const unsigned short* gAl1 = nullptr;
  const unsigned short* gBl0 = nullptr; const unsigned short* gBl1 = nullptr;
  if constexpr (SPLIT) {
    gAl0 = Al + (size_t)(m0 + row0) * K + ce;
    gAl1 = Al + (size_t)(m0 + row1) * K + ce;
    gBl0 = Bl + (size_t)(n0 + row0) * K + ce;
    gBl1 = Bl + (size_t)(n0 + row1) * K + ce;
  }
  unsigned short* lA0 = &sAh[wave * 1024];
  unsigned short* lA1 = &sAh[wave * 1024 + 512];
  unsigned short* lB0 = &sBh[wave * 1024];
  unsigned short* lB1 = &sBh[wave * 1024 + 512];
  unsigned short* lAl0 = SPLIT ? &sAl[wave * 1024] : nullptr;
  unsigned short* lAl1 = SPLIT ? &sAl[wave * 1024 + 512] : nullptr;
  unsigned short* lBl0 = SPLIT ? &sBl[wave * 1024] : nullptr;
  unsigned short* lBl1 = SPLIT ? &sBl[wave * 1024 + 512] : nullptr;

  const int nk = K >> 5;
  for (int ks = 0; ks < nk; ++ks) {
    gload16(gA0, lA0); gload16(gA1, lA1);
    gload16(gB0, lB0); gload16(gB1, lB1);
    if constexpr (SPLIT) {
      gload16(gAl0, lAl0); gload16(gAl1, lAl1);
      gload16(gBl0, lBl0); gload16(gBl1, lBl1);
    }
    gA0 += 32; gA1 += 32; gB0 += 32; gB1 += 32;
    if constexpr (SPLIT) { gAl0 += 32; gAl1 += 32; gBl0 += 32; gBl1 += 32; }
    __syncthreads();

    u16x8 fa[4], fb[4], fal[4], fbl[4];
    #pragma unroll
    for (int i = 0; i < 4; ++i) {
      const int ra = (wr * 64 + i * 16 + lr) * 32 + ls * 8;
      const int rb = (wc * 64 + i * 16 + lr) * 32 + ls * 8;
      fa[i] = *(const u16x8*)&sAh[ra];
      fb[i] = *(const u16x8*)&sBh[rb];
      if constexpr (SPLIT) {
        fal[i] = *(const u16x8*)&sAl[ra];
        fbl[i] = *(const u16x8*)&sBl[rb];
      }
    }
    #pragma unroll
    for (int i = 0; i < 4; ++i)
      #pragma unroll
      for (int j = 0; j < 4; ++j) {
        acc[i][j] = mfma16(fa[i], fb[j], acc[i][j]);
        if constexpr (SPLIT) {
          acc[i][j] = mfma16(fal[i], fb[j], acc[i][j]);
          acc[i][j] = mfma16(fa[i], fbl[j], acc[i][j]);
        }
      }
    __syncthreads();
  }

  #pragma unroll
  for (int i = 0; i < 4; ++i) {
    const int rrow = m0 + wr * 64 + i * 16 + ls * 4;
    #pragma unroll
    for (int j = 0; j < 4; ++j) {
      const int col = n0 + wc * 64 + j * 16 + lr;
      #pragma unroll
      for (int q = 0; q < 4; ++q)
        C[(size_t)(rrow + q) * N + col] = acc[i][j][q];
    }
  }
}

// -------- row softmax + top-2 + P(bf16) + idx write / queue ambiguous --------
__global__ __launch_bounds__(256) void softmax_k(
    const float* __restrict__ S, unsigned short* __restrict__ P,
    int* __restrict__ idx, int* __restrict__ queue,
    int* __restrict__ qcount, int baseRow) {
  const int widx = blockIdx.x * 4 + (threadIdx.x >> 6);
  const int lane = threadIdx.x & 63;
  const float* srow = S + (size_t)widx * MDIM;
  float4 v[8];
  float m1 = -3.4e38f, m2 = -3.4e38f;
  int i1 = 0x7fffffff, i2 = 0x7fffffff;
  #pragma unroll
  for (int i = 0; i < 8; ++i) {
    v[i] = *(const float4*)(srow + i * 256 + lane * 4);
    const float xs[4] = {v[i].x, v[i].y, v[i].z, v[i].w};
    #pragma unroll
    for (int q = 0; q < 4; ++q) {
      const float x = xs[q];
      const int ii = i * 256 + lane * 4 + q;
      if (x > m1 || (x == m1 && ii < i1)) { m2 = m1; i2 = i1; m1 = x; i1 = ii; }
      else if (x > m2 || (x == m2 && ii < i2)) { m2 = x; i2 = ii; }
    }
  }
  #pragma unroll
  for (int off = 1; off < 64; off <<= 1) {  // butterfly top-2 merge
    const float n1 = __shfl_xor(m1, off), n2 = __shfl_xor(m2, off);
    const int j1 = __shfl_xor(i1, off), j2 = __shfl_xor(i2, off);
    if (n1 > m1 || (n1 == m1 && j1 < i1)) {
      if (m1 > n2 || (m1 == n2 && i1 < j2)) { m2 = m1; i2 = i1; }
      else { m2 = n2; i2 = j2; }
      m1 = n1; i1 = j1;
    } else if (n1 > m2 || (n1 == m2 && j1 < i2)) { m2 = n1; i2 = j1; }
  }
  float sum = 0.0f;
  #pragma unroll
  for (int i = 0; i < 8; ++i) {
    v[i].x = __expf(SCALE_F * (v[i].x - m1)); sum += v[i].x;
    v[i].y = __expf(SCALE_F * (v[i].y - m1)); sum += v[i].y;
    v[i].z = __expf(SCALE_F * (v[i].z - m1)); sum += v[i].z;
    v[i].w = __expf(SCALE_F * (v[i].w - m1)); sum += v[i].w;
  }
  #pragma unroll
  for (int off = 1; off < 64; off <<= 1) sum += __shfl_xor(sum, off);
  const float rs = 1.0f / sum;
  #pragma unroll
  for (int i = 0; i < 8; ++i) {
    ushort4 pk;
    pk.x = f2bf(v[i].x * rs); pk.y = f2bf(v[i].y * rs);
    pk.z = f2bf(v[i].z * rs); pk.w = f2bf(v[i].w * rs);
    *(ushort4*)(P + (size_t)widx * MDIM + i * 256 + lane * 4) = pk;
  }
  const int tok = baseRow + widx;
  if (lane == 0) {
    idx[tok] = i1;                      // placeholder; refine2 may overwrite
    if (m1 - m2 < TAU_BF) {             // ambiguous -> split-GEMM refine
      int slot = atomicAdd(qcount, 1);
      if (slot < QCAP) queue[slot] = tok;
    }
  }
}

// ------- gather queued tokens' normalized rows -> compact hi/lo matrix -------
__global__ __launch_bounds__(256) void gather_prep_k(
    const int* __restrict__ queue, const int* __restrict__ qcount,
    const float* __restrict__ inp, const float* __restrict__ inv_n,
    unsigned short* __restrict__ Qh, unsigned short* __restrict__ Ql) {
  const int w = blockIdx.x * 4 + (threadIdx.x >> 6);
  const int lane = threadIdx.x & 63;
  int cnt = *qcount; if (cnt > QCAP) cnt = QCAP;
  if (w >= cnt) return;
  const int tok = queue[w];
  const float rn = inv_n[tok];
  const float* x = inp + (size_t)tok * FDIM;
  #pragma unroll
  for (int h = 0; h < 2; ++h) {
    float4 xv = *(const float4*)(x + h * 256 + lane * 4);
    float vv[4] = {xv.x, xv.y, xv.z, xv.w};
    ushort4 hs, lo;
    #pragma unroll
    for (int q = 0; q < 4; ++q) {
      float v = vv[q] * rn;
      unsigned short hb = f2bf(v);
      ((unsigned short*)&hs)[q] = hb;
      ((unsigned short*)&lo)[q] = f2bf(v - bf2f(hb));
    }
    const size_t e = (size_t)w * FDIM + h * 256 + lane * 4;
    *(ushort4*)(Qh + e) = hs;
    *(ushort4*)(Ql + e) = lo;
  }
}

// ------- level-2: full-row top-2 on split-S; fp64 pair-decide; write idx -------
__global__ __launch_bounds__(256) void refine2_k(
    const int* __restrict__ queue, const int* __restrict__ qcount,
    const float* __restrict__ Sref, const float* __restrict__ inp,
    const float* __restrict__ mem, int* __restrict__ idx) {
  const int w = blockIdx.x * 4 + (threadIdx.x >> 6);
  const int lane = threadIdx.x & 63;
  int cnt = *qcount; if (cnt > QCAP) cnt = QCAP;
  if (w >= cnt) return;
  const int tok = queue[w];
  const float* srow = Sref + (size_t)w * MDIM;
  float m1 = -3.4e38f, m2 = -3.4e38f;
  int i1 = 0x7fffffff, i2 = 0x7fffffff;
  #pragma unroll
  for (int i = 0; i < 8; ++i) {
    const float4 vv = *(const float4*)(srow + i * 256 + lane * 4);
    const float xs[4] = {vv.x, vv.y, vv.z, vv.w};
    #pragma unroll
    for (int q = 0; q < 4; ++q) {
      const float x = xs[q];
      const int ii = i * 256 + lane * 4 + q;
      if (x > m1 || (x == m1 && ii < i1)) { m2 = m1; i2 = i1; m1 = x; i1 = ii; }
      else if (x > m2 || (x == m2 && ii < i2)) { m2 = x; i2 = ii; }
    }
  }
  #pragma unroll
  for (int off = 1; off < 64; off <<= 1) {
    const float n1 = __shfl_xor(m1, off), n2 = __shfl_xor(m2, off);
    const int j1 = __shfl_xor(i1, off), j2 = __shfl_xor(i2, off);
    if (n1 > m1 || (n1 == m1 && j1 < i1)) {
      if (m1 > n2 || (m1 == n2 && i1 < j2)) { m2 = m1; i2 = i1; }
      else { m2 = n2; i2 = j2; }
      m1 = n1; i1 = j1;
    } else if (n1 > m2 || (n1 == m2 && j1 < i2)) { m2 = n1; i2 = j1; }
  }
  int pick = i1;
  if (m1 - m2 < TAU_SP) {  // near-tie even at split accuracy -> fp64 decides
    const int a = (i1 < i2) ? i1 : i2, b = (i1 < i2) ? i2 : i1;
    const float* x = inp + (size_t)tok * FDIM;
    const float* ma = mem + (size_t)a * FDIM;
    const float* mb = mem + (size_t)b * FDIM;
    double da = 0, db = 0, na = 0, nb = 0;
    #pragma unroll
    for (int j = 0; j < 8; ++j) {
      const int e = lane * 8 + j;
      const double xv = x[e], av = ma[e], bv = mb[e];
      da += xv * av; na += av * av;
      db += xv * bv; nb += bv * bv;
    }
    #pragma unroll
    for (int off = 1; off < 64; off <<= 1) {
      da += __shfl_xor(da, off); na += __shfl_xor(na, off);
      db += __shfl_xor(db, off); nb += __shfl_xor(nb, off);
    }
    const double d1 = da / sqrt(fmax(na, 1e-12));
    const double d2 = db / sqrt(fmax(nb, 1e-12));
    if (d2 > d1) pick = b;
    else pick = a;                      // includes exact tie: smaller index
  }
  if (lane == 0) idx[tok] = pick;
}

// ------- deterministic segment-sum: one block per code, no atomics -------
// Scans idx in 4096-token windows; matches collected to LDS (sorted per
// window -> globally ascending order), rows accumulated into registers.
__global__ __launch_bounds__(256) void segsum_k(
    const int* __restrict__ idx, const float* __restrict__ inp,
    const float* __restrict__ inv_n, float* __restrict__ updates) {
  __shared__ int lst[256];
  __shared__ int lcnt;
  const int m = blockIdx.x;
  const int t = threadIdx.x;
  float a0 = 0.f, a1 = 0.f;             // features 2t, 2t+1
  for (int base = 0; base < N_TOK; base += 4096) {
    if (t == 0) lcnt = 0;
    __syncthreads();
    #pragma unroll
    for (int u = 0; u < 4; ++u) {
      const int off4 = (u * 256 + t) * 4;               // coalesced int4
      const int4 v = *(const int4*)&idx[base + off4];
      if (v.x == m) { int p = atomicAdd(&lcnt, 1); if (p < 256) lst[p] = base + off4 + 0; }
      if (v.y == m) { int p = atomicAdd(&lcnt, 1); if (p < 256) lst[p] = base + off4 + 1; }
      if (v.z == m) { int p = atomicAdd(&lcnt, 1); if (p < 256) lst[p] = base + off4 + 2; }
      if (v.w == m) { int p = atomicAdd(&lcnt, 1); if (p < 256) lst[p] = base + off4 + 3; }
    }
    __syncthreads();
    int c = lcnt; if (c > 256) c = 256;
    if (t == 0 && c > 1) {              // insertion sort (tiny list)
      for (int i = 1; i < c; ++i) {
        int key = lst[i], j = i - 1;
        while (j >= 0 && lst[j] > key) { lst[j + 1] = lst[j]; --j; }
        lst[j + 1] = key;
      }
    }
    __syncthreads();
    for (int i = 0; i < c; ++i) {
      const int tok = lst[i];
      const float rn = inv_n[tok];
      const float2 xv = *(const float2*)&inp[(size_t)tok * FDIM + t * 2];
      a0 += xv.x * rn; a1 += xv.y * rn;
    }
    __syncthreads();                    // protect lst/lcnt before next window
  }
  *(float2*)&updates[(size_t)m * FDIM + t * 2] = make_float2(a0, a1);
}

// ---------------- final blend (fp32 out) ----------------
__global__ __launch_bounds__(256) void final_update_k(
    const float* __restrict__ mem, const float* __restrict__ upd,
    float* __restrict__ out) {
  const size_t i = ((size_t)blockIdx.x * 256 + threadIdx.x) * 4;
  float4 m = *(const float4*)(mem + i);
  float4 u = *(const float4*)(upd + i);
  float4 r;
  r.x = m.x * 0.9f + u.x * 0.1f;
  r.y = m.y * 0.9f + u.y * 0.1f;
  r.z = m.z * 0.9f + u.z * 0.1f;
  r.w = m.w * 0.9f + u.w * 0.1f;
  *(float4*)(out + i) = r;
}

extern "C" void kernel_launch(void* const* d_in, const int* in_sizes, int n_in,
                              void* d_out, int out_size, void* d_ws, size_t ws_size,
                              hipStream_t stream) {
  const float* inputs = (const float*)d_in[0];
  const float* memory = (const float*)d_in[1];
  if (n_in >= 2 && in_sizes[0] != N_TOK * FDIM) {  // order guard
    inputs = (const float*)d_in[1];
    memory = (const float*)d_in[0];
  }
  float* out_mu = (float*)d_out;                       // [N][F] fp32
  float* out_um = out_mu + (size_t)N_TOK * FDIM;       // [M][F] fp32

  char* base = (char*)d_ws;
  size_t off = 0;
  auto take = [&](size_t bytes) -> char* {
    char* p = base + off;
    off = (off + bytes + 255) & ~(size_t)255;
    return p;
  };
  unsigned short* Bh = (unsigned short*)take((size_t)MDIM * FDIM * 2);
  unsigned short* Bl = (unsigned short*)take((size_t)MDIM * FDIM * 2);
  unsigned short* Bt = (unsigned short*)take((size_t)MDIM * FDIM * 2);
  float* inv_n = (float*)take((size_t)N_TOK * 4);
  float* updates = (float*)take((size_t)MDIM * FDIM * 4);
  int* idx = (int*)take((size_t)N_TOK * 4);
  int* queue = (int*)take((size_t)QCAP * 4);
  int* qcount = (int*)take(256);
  unsigned short* Qh = (unsigned short*)take((size_t)QCAP * FDIM * 2);
  unsigned short* Ql = (unsigned short*)take((size_t)QCAP * FDIM * 2);
  float* Sref = (float*)take((size_t)QCAP * MDIM * 4);
  const size_t fixed = off;

  int chunkT = 16384;  // per-pass token chunk; shrink to fit ws
  while (chunkT > 128 && fixed + (size_t)chunkT * 13312 + 4096 > ws_size)
    chunkT >>= 1;
  if (fixed + (size_t)chunkT * 13312 + 4096 > ws_size) return;  // ws too small

  unsigned short* Ah = (unsigned short*)take((size_t)chunkT * FDIM * 2);
  float* Sbuf = (float*)take((size_t)chunkT * MDIM * 4);
  unsigned short* Pbuf = (unsigned short*)take((size_t)chunkT * MDIM * 2);

  zero_k<<<1, 64, 0, stream>>>(qcount);
  prep_memory_k<<<MDIM, 64, 0, stream>>>(memory, Bh, Bl);
  transpose_k<<<dim3(MDIM / 32, FDIM / 32), 256, 0, stream>>>(Bh, Bt);
  input_norms_k<<<N_TOK / 4, 256, 0, stream>>>(inputs, inv_n);

  const int nby = chunkT / 128;
  for (int baseRow = 0; baseRow < N_TOK; baseRow += chunkT) {
    prep_a_k<<<chunkT / 2, 256, 0, stream>>>(inputs, inv_n, Ah, baseRow);
    gemm_bt_k<false, true><<<16 * nby, 256, 0, stream>>>(
        Ah, nullptr, Bh, nullptr, Sbuf, MDIM, FDIM, 4, nullptr);
    softmax_k<<<chunkT / 4, 256, 0, stream>>>(
        Sbuf, Pbuf, idx, queue, qcount, baseRow);
    gemm_bt_k<false, true><<<4 * nby, 256, 0, stream>>>(
        Pbuf, nullptr, Bt, nullptr, out_mu + (size_t)baseRow * FDIM,
        FDIM, MDIM, 2, nullptr);
  }
  // two-level argmax refine: gather ambiguous rows, split-GEMM, decide idx
  gather_prep_k<<<QCAP / 4, 256, 0, stream>>>(queue, qcount, inputs, inv_n, Qh, Ql);
  gemm_bt_k<true, false><<<16 * (QCAP / 128), 256, 0, stream>>>(
      Qh, Ql, Bh, Bl, Sref, MDIM, FDIM, 4, qcount);
  refine2_k<<<QCAP / 4, 256, 0, stream>>>(queue, qcount, Sref, inputs, memory, idx);
  // deterministic segment-sum (no atomics), then blend
  segsum_k<<<MDIM, 256, 0, stream>>>(idx, inputs, inv_n, updates);
  final_update_k<<<(MDIM * FDIM / 4) / 256, 256, 0, stream>>>(memory, updates, out_um);
}